// Round 1
// baseline (2414.729 us; speedup 1.0000x reference)
//
#include <hip/hip_runtime.h>

#define BATCH 4
#define NFEAT 64
#define DGRP 8
#define HH 96
#define WW 96
#define HWP (HH*WW)

// ---------------------------------------------------------------------------
// Weight prep: transpose every weight tensor from (OC, ICpg, 3, 3) row-major
// into [(ic*9+k)*OC + oc] so that for a fixed (ic,k) the OC weights are
// contiguous -> wave-uniform reads scalarize to s_load_dwordx8/16 and feed
// v_fmac SGPR operands (avoids LDS-broadcast ds_read issue-bandwidth wall).
// ---------------------------------------------------------------------------
struct PrepArgs {
  const float* src[20];
  int ocn[20];
  int ick[20];
  int base[21];
};

__global__ __launch_bounds__(256) void prep_kernel(PrepArgs a, float* __restrict__ dst) {
  int gid = blockIdx.x * 256 + threadIdx.x;
  if (gid >= a.base[20]) return;
  int t = 0;
  while (gid >= a.base[t + 1]) ++t;
  int local = gid - a.base[t];
  int OC = a.ocn[t], ICK = a.ick[t];
  int ik = local / OC;
  int oc = local - ik * OC;
  dst[gid] = a.src[t][oc * ICK + ik];  // dst enumerated in [(ik)*OC+oc] order
}

// ---------------------------------------------------------------------------
// Grouped 3x3 conv, pad=1 dil=1, groups=8, 64 out channels.
// CPG = in-channels per group (8 or 16). INTERLEAVE: channel c of the virtual
// concat input is in0[c/2] (c even) / in1[c/2] (c odd)  [= _cat_align].
// Block (32,8), tile 32x8, each thread computes its pixel for the 8 out
// channels of its group. Grid (3, 12, BATCH*8).
// ---------------------------------------------------------------------------
template <int CPG, bool LRELU, bool INTERLEAVE>
__global__ __launch_bounds__(256) void gconv_kernel(
    const float* __restrict__ in0, const float* __restrict__ in1,
    const float* __restrict__ wT,   // [(j*9+k)*64 + oc_global]
    const float* __restrict__ bias, float* __restrict__ out) {
  const int tx = threadIdx.x, ty = threadIdx.y;
  const int bx = blockIdx.x * 32, by = blockIdx.y * 8;
  const int g = blockIdx.z & 7, b = blockIdx.z >> 3;

  __shared__ float sIn[CPG][10][34];
  const int lid = ty * 32 + tx;
  for (int i = lid; i < CPG * 340; i += 256) {
    int xx = i % 34;
    int r = i / 34;
    int yy = r % 10;
    int j = r / 10;
    int gx = bx + xx - 1, gy = by + yy - 1;
    float v = 0.f;
    if (gx >= 0 && gx < WW && gy >= 0 && gy < HH) {
      const float* src;
      int ch;
      if (INTERLEAVE) {
        src = (j & 1) ? in1 : in0;
        ch = g * (CPG / 2) + (j >> 1);
      } else {
        src = in0;
        ch = g * CPG + j;
      }
      v = src[((size_t)b * NFEAT + ch) * HWP + gy * WW + gx];
    }
    sIn[j][yy][xx] = v;
  }
  __syncthreads();

  float acc[8];
#pragma unroll
  for (int o = 0; o < 8; ++o) acc[o] = bias[g * 8 + o];

  for (int j = 0; j < CPG; ++j) {
#pragma unroll
    for (int k = 0; k < 9; ++k) {
      float v = sIn[j][ty + k / 3][tx + k % 3];
      const float* wp = wT + (j * 9 + k) * 64 + g * 8;  // uniform -> s_load
#pragma unroll
      for (int o = 0; o < 8; ++o) acc[o] = fmaf(v, wp[o], acc[o]);
    }
  }
  const int y = by + ty, x = bx + tx;
#pragma unroll
  for (int o = 0; o < 8; ++o) {
    float v = acc[o];
    if (LRELU) v = (v >= 0.f) ? v : 0.1f * v;
    out[((size_t)b * NFEAT + g * 8 + o) * HWP + y * WW + x] = v;
  }
}

// ---------------------------------------------------------------------------
// Offset/mask conv: 64 -> 216 channels, 3x3, dilation D, pad D (no groups,
// no activation). Block (16,8) over a 32x8 pixel tile: each thread handles
// 2 pixels (x, x+16) so the 24-weight uniform load amortizes over 48 fmacs.
// Grid (3, 12, BATCH*9): blockIdx.z%9 selects the 24-out-channel slab.
// ---------------------------------------------------------------------------
template <int D>
__global__ __launch_bounds__(128) void omconv_kernel(
    const float* __restrict__ in, const float* __restrict__ wT,  // [(c*9+k)*216 + oc]
    const float* __restrict__ bias, float* __restrict__ out) {
  constexpr int TW2 = 32 + 2 * D, TH2 = 8 + 2 * D;
  const int tx = threadIdx.x, ty = threadIdx.y;
  const int bx = blockIdx.x * 32, by = blockIdx.y * 8;
  const int ob = (blockIdx.z % 9) * 24;
  const int b = blockIdx.z / 9;

  __shared__ float sIn[8 * TH2 * TW2];
  float acc0[24], acc1[24];
#pragma unroll
  for (int o = 0; o < 24; ++o) {
    acc0[o] = 0.f;
    acc1[o] = 0.f;
  }

  const int lid = ty * 16 + tx;
  for (int icc = 0; icc < 8; ++icc) {  // 8 chunks of 8 input channels
    __syncthreads();
    for (int i = lid; i < 8 * TH2 * TW2; i += 128) {
      int xx = i % TW2;
      int r = i / TW2;
      int yy = r % TH2;
      int c = r / TH2;
      int gx = bx + xx - D, gy = by + yy - D;
      float v = 0.f;
      if (gx >= 0 && gx < WW && gy >= 0 && gy < HH)
        v = in[((size_t)b * NFEAT + icc * 8 + c) * HWP + gy * WW + gx];
      sIn[i] = v;
    }
    __syncthreads();
    for (int c = 0; c < 8; ++c) {
#pragma unroll
      for (int k = 0; k < 9; ++k) {
        const float* row = &sIn[(c * TH2 + ty + (k / 3) * D) * TW2 + tx + (k % 3) * D];
        float v0 = row[0], v1 = row[16];
        const float* wp = wT + ((icc * 8 + c) * 9 + k) * 216 + ob;  // uniform
#pragma unroll
        for (int o = 0; o < 24; ++o) {
          acc0[o] = fmaf(v0, wp[o], acc0[o]);
          acc1[o] = fmaf(v1, wp[o], acc1[o]);
        }
      }
    }
  }
  const int y = by + ty;
#pragma unroll
  for (int o = 0; o < 24; ++o) {
    float bsv = bias[ob + o];
    size_t basei = ((size_t)b * 216 + ob + o) * HWP + y * WW + bx + tx;
    out[basei] = acc0[o] + bsv;
    out[basei + 16] = acc1[o] + bsv;
  }
}

// ---------------------------------------------------------------------------
// Modulated deformable conv (DCNv2), stride 1, 3x3, dilation D, pad D,
// deformable_groups = 8 (weights are full 64x64x9). om holds the raw
// offset-mask conv output (216 ch): ch dg*18+2k = dy, +1 = dx,
// ch 144+dg*9+k = mask logit (sigmoid applied here).
// Block (16,8) = one pixel/thread; blockIdx.z = b*2 + oc_half (32 oc each).
// No LDS: weights are wave-uniform contiguous global reads (s_load),
// bilinear corner gathers hit L1 (offsets are small).
// ---------------------------------------------------------------------------
template <int D, bool LRELU>
__global__ __launch_bounds__(128) void dcn_kernel(
    const float* __restrict__ x, const float* __restrict__ om,
    const float* __restrict__ wT,  // [(c*9+k)*64 + oc]
    const float* __restrict__ bias, float* __restrict__ out) {
  const int tx = threadIdx.x, ty = threadIdx.y;
  const int xp = blockIdx.x * 16 + tx;
  const int yp = blockIdx.y * 8 + ty;
  const int oh = blockIdx.z & 1, b = blockIdx.z >> 1;
  const int ob = oh * 32;

  float acc[32];
#pragma unroll
  for (int o = 0; o < 32; ++o) acc[o] = 0.f;

  const size_t bOM = (size_t)b * 216 * HWP;
  const int pix = yp * WW + xp;
  const float* xb = x + (size_t)b * NFEAT * HWP;

  for (int dg = 0; dg < 8; ++dg) {
    for (int k = 0; k < 9; ++k) {
      float dy = om[bOM + (size_t)(dg * 18 + 2 * k) * HWP + pix];
      float dxv = om[bOM + (size_t)(dg * 18 + 2 * k + 1) * HWP + pix];
      float mr = om[bOM + (size_t)(144 + dg * 9 + k) * HWP + pix];
      float m = 1.f / (1.f + __expf(-mr));
      float py = (float)(yp + (k / 3 - 1) * D) + dy;
      float px = (float)(xp + (k % 3 - 1) * D) + dxv;
      float y0f = floorf(py), x0f = floorf(px);
      float ly = py - y0f, lx = px - x0f;
      int y0 = (int)y0f, x0 = (int)x0f;
      int y1 = y0 + 1, x1 = x0 + 1;
      bool vy0 = (unsigned)y0 < (unsigned)HH, vy1 = (unsigned)y1 < (unsigned)HH;
      bool vx0 = (unsigned)x0 < (unsigned)WW, vx1 = (unsigned)x1 < (unsigned)WW;
      int cy0 = min(max(y0, 0), HH - 1), cy1 = min(max(y1, 0), HH - 1);
      int cx0 = min(max(x0, 0), WW - 1), cx1 = min(max(x1, 0), WW - 1);
      float w00 = (1.f - ly) * (1.f - lx) * m, w01 = (1.f - ly) * lx * m;
      float w10 = ly * (1.f - lx) * m, w11 = ly * lx * m;
      int i00 = cy0 * WW + cx0, i01 = cy0 * WW + cx1;
      int i10 = cy1 * WW + cx0, i11 = cy1 * WW + cx1;
#pragma unroll
      for (int c = 0; c < 8; ++c) {
        const float* xc = xb + (size_t)(dg * 8 + c) * HWP;
        float v00 = (vy0 && vx0) ? xc[i00] : 0.f;
        float v01 = (vy0 && vx1) ? xc[i01] : 0.f;
        float v10 = (vy1 && vx0) ? xc[i10] : 0.f;
        float v11 = (vy1 && vx1) ? xc[i11] : 0.f;
        float val = w00 * v00 + w01 * v01 + w10 * v10 + w11 * v11;
        const float* wp = wT + ((dg * 8 + c) * 9 + k) * 64 + ob;  // uniform
#pragma unroll
        for (int o = 0; o < 32; ++o) acc[o] = fmaf(val, wp[o], acc[o]);
      }
    }
  }
#pragma unroll
  for (int o = 0; o < 32; ++o) {
    float v = acc[o] + bias[ob + o];
    if (LRELU) v = (v >= 0.f) ? v : 0.1f * v;
    out[((size_t)b * NFEAT + ob + o) * HWP + pix] = v;
  }
}

// ---------------------------------------------------------------------------
extern "C" void kernel_launch(void* const* d_in, const int* in_sizes, int n_in,
                              void* d_out, int out_size, void* d_ws, size_t ws_size,
                              hipStream_t stream) {
  const float* nbr = (const float*)d_in[0];
  const float* ref = (const float*)d_in[1];
  auto f = [&](int i) { return (const float*)d_in[i]; };

  float* ws = (float*)d_ws;
  const size_t FSZ = (size_t)BATCH * NFEAT * HWP;   // 2,359,296 floats
  const size_t OMSZ = (size_t)BATCH * 216 * HWP;    // 7,962,624 floats
  float* bufA = ws;
  float* bufB = ws + FSZ;
  float* bufC = ws + 2 * FSZ;
  float* bufD = ws + 3 * FSZ;
  float* omB = ws + 4 * FSZ;
  float* wts = ws + 4 * FSZ + OMSZ;  // 737,280 floats of transposed weights

  // ---- weight transpose prep (one launch, every call) ----
  // order: l3{oc1,oc2,om,dcn} l2{oc1,oc2,oc3,om,dcn,fc} l1{same} cas{oc1,oc2,om,dcn}
  static const int srcIdx[20] = {2, 4, 6, 8, 10, 12, 14, 18, 20, 16,
                                 22, 24, 26, 30, 32, 28, 34, 36, 38, 40};
  static const int ocnA[20] = {64, 64, 216, 64, 64, 64, 64, 216, 64, 64,
                               64, 64, 64, 216, 64, 64, 64, 64, 216, 64};
  static const int ickA[20] = {144, 72, 576, 576, 144, 144, 72, 576, 576, 144,
                               144, 144, 72, 576, 576, 144, 144, 72, 576, 576};
  PrepArgs pa;
  int base = 0;
  const float* wt[20];
  for (int t = 0; t < 20; ++t) {
    pa.src[t] = f(srcIdx[t]);
    pa.ocn[t] = ocnA[t];
    pa.ick[t] = ickA[t];
    pa.base[t] = base;
    wt[t] = wts + base;
    base += ocnA[t] * ickA[t];
  }
  pa.base[20] = base;  // 737,280
  prep_kernel<<<(base + 255) / 256, 256, 0, stream>>>(pa, wts);

  dim3 gcGrid(3, 12, BATCH * 8), gcBlk(32, 8);
  dim3 omGrid(3, 12, BATCH * 9), omBlk(16, 8);
  dim3 dcGrid(6, 12, BATCH * 2), dcBlk(16, 8);

  // ---- level 3 (dilation 5) ----
  gconv_kernel<16, true, true><<<gcGrid, gcBlk, 0, stream>>>(nbr, ref, wt[0], f(3), bufA);
  gconv_kernel<8, true, false><<<gcGrid, gcBlk, 0, stream>>>(bufA, nullptr, wt[1], f(5), bufB);
  omconv_kernel<5><<<omGrid, omBlk, 0, stream>>>(bufB, wt[2], f(7), omB);
  dcn_kernel<5, true><<<dcGrid, dcBlk, 0, stream>>>(nbr, omB, wt[3], f(9), bufC);
  // bufB = to (off_l3), bufC = tf (feat_l3)

  // ---- level 2 (dilation 3) ----
  gconv_kernel<16, true, true><<<gcGrid, gcBlk, 0, stream>>>(nbr, ref, wt[4], f(11), bufA);
  gconv_kernel<16, true, true><<<gcGrid, gcBlk, 0, stream>>>(bufA, bufB, wt[5], f(13), bufD);
  gconv_kernel<8, true, false><<<gcGrid, gcBlk, 0, stream>>>(bufD, nullptr, wt[6], f(15), bufA);
  omconv_kernel<3><<<omGrid, omBlk, 0, stream>>>(bufA, wt[7], f(19), omB);
  dcn_kernel<3, false><<<dcGrid, dcBlk, 0, stream>>>(nbr, omB, wt[8], f(21), bufB);
  gconv_kernel<16, true, true><<<gcGrid, gcBlk, 0, stream>>>(bufB, bufC, wt[9], f(17), bufD);
  // bufA = to (off_l2), bufD = tf (feat_l2)

  // ---- level 1 (dilation 1) ----
  gconv_kernel<16, true, true><<<gcGrid, gcBlk, 0, stream>>>(nbr, ref, wt[10], f(23), bufB);
  gconv_kernel<16, true, true><<<gcGrid, gcBlk, 0, stream>>>(bufB, bufA, wt[11], f(25), bufC);
  gconv_kernel<8, true, false><<<gcGrid, gcBlk, 0, stream>>>(bufC, nullptr, wt[12], f(27), bufB);
  omconv_kernel<1><<<omGrid, omBlk, 0, stream>>>(bufB, wt[13], f(31), omB);
  dcn_kernel<1, false><<<dcGrid, dcBlk, 0, stream>>>(nbr, omB, wt[14], f(33), bufC);
  gconv_kernel<16, false, true><<<gcGrid, gcBlk, 0, stream>>>(bufC, bufD, wt[15], f(29), bufA);
  // bufA = feat after l1 (no lrelu)

  // ---- cascade (dilation 1) ----
  gconv_kernel<16, true, true><<<gcGrid, gcBlk, 0, stream>>>(bufA, ref, wt[16], f(35), bufB);
  gconv_kernel<8, true, false><<<gcGrid, gcBlk, 0, stream>>>(bufB, nullptr, wt[17], f(37), bufC);
  omconv_kernel<1><<<omGrid, omBlk, 0, stream>>>(bufC, wt[18], f(39), omB);
  dcn_kernel<1, true><<<dcGrid, dcBlk, 0, stream>>>(bufA, omB, wt[19], f(41), (float*)d_out);
}

// Round 2
// 1832.179 us; speedup vs baseline: 1.3180x; 1.3180x over previous
//
#include <hip/hip_runtime.h>

#define BATCH 4
#define NFEAT 64
#define DGRP 8
#define HH 96
#define WW 96
#define HWP (HH*WW)

// ---------------------------------------------------------------------------
// Weight prep: transpose every weight tensor from (OC, ICpg, 3, 3) row-major
// into [(ic*9+k)*OC + oc] so that for a fixed (ic,k) the OC weights are
// contiguous -> wave-uniform reads scalarize to s_load (SGPR=112 in R0
// confirmed this works).
// ---------------------------------------------------------------------------
struct PrepArgs {
  const float* src[20];
  int ocn[20];
  int ick[20];
  int base[21];
};

__global__ __launch_bounds__(256) void prep_kernel(PrepArgs a, float* __restrict__ dst) {
  int gid = blockIdx.x * 256 + threadIdx.x;
  if (gid >= a.base[20]) return;
  int t = 0;
  while (gid >= a.base[t + 1]) ++t;
  int local = gid - a.base[t];
  int OC = a.ocn[t], ICK = a.ick[t];
  int ik = local / OC;
  int oc = local - ik * OC;
  dst[gid] = a.src[t][oc * ICK + ik];
}

// ---------------------------------------------------------------------------
// Channel-major (b,64,hw) -> pixel-major (b,hw,64) transpose via LDS.
// Grid (HWP/64, BATCH), block (64,4). Coalesced on both sides.
// ---------------------------------------------------------------------------
__global__ __launch_bounds__(256) void transpose_kernel(
    const float* __restrict__ in, float* __restrict__ out) {
  __shared__ float s[64][65];
  const int p0 = blockIdx.x * 64;
  const int b = blockIdx.y;
  const int tx = threadIdx.x, ty = threadIdx.y;
  for (int c = ty; c < 64; c += 4)
    s[c][tx] = in[((size_t)b * NFEAT + c) * HWP + p0 + tx];
  __syncthreads();
  for (int p = ty; p < 64; p += 4)
    out[((size_t)b * HWP + p0 + p) * NFEAT + tx] = s[tx][p];
}

// ---------------------------------------------------------------------------
// Grouped 3x3 conv, pad=1 dil=1, groups=8, 64 out channels. (unchanged R0)
// ---------------------------------------------------------------------------
template <int CPG, bool LRELU, bool INTERLEAVE>
__global__ __launch_bounds__(256) void gconv_kernel(
    const float* __restrict__ in0, const float* __restrict__ in1,
    const float* __restrict__ wT,   // [(j*9+k)*64 + oc_global]
    const float* __restrict__ bias, float* __restrict__ out) {
  const int tx = threadIdx.x, ty = threadIdx.y;
  const int bx = blockIdx.x * 32, by = blockIdx.y * 8;
  const int g = blockIdx.z & 7, b = blockIdx.z >> 3;

  __shared__ float sIn[CPG][10][34];
  const int lid = ty * 32 + tx;
  for (int i = lid; i < CPG * 340; i += 256) {
    int xx = i % 34;
    int r = i / 34;
    int yy = r % 10;
    int j = r / 10;
    int gx = bx + xx - 1, gy = by + yy - 1;
    float v = 0.f;
    if (gx >= 0 && gx < WW && gy >= 0 && gy < HH) {
      const float* src;
      int ch;
      if (INTERLEAVE) {
        src = (j & 1) ? in1 : in0;
        ch = g * (CPG / 2) + (j >> 1);
      } else {
        src = in0;
        ch = g * CPG + j;
      }
      v = src[((size_t)b * NFEAT + ch) * HWP + gy * WW + gx];
    }
    sIn[j][yy][xx] = v;
  }
  __syncthreads();

  float acc[8];
#pragma unroll
  for (int o = 0; o < 8; ++o) acc[o] = bias[g * 8 + o];

  for (int j = 0; j < CPG; ++j) {
#pragma unroll
    for (int k = 0; k < 9; ++k) {
      float v = sIn[j][ty + k / 3][tx + k % 3];
      const float* wp = wT + (j * 9 + k) * 64 + g * 8;  // uniform -> s_load
#pragma unroll
      for (int o = 0; o < 8; ++o) acc[o] = fmaf(v, wp[o], acc[o]);
    }
  }
  const int y = by + ty, x = bx + tx;
#pragma unroll
  for (int o = 0; o < 8; ++o) {
    float v = acc[o];
    if (LRELU) v = (v >= 0.f) ? v : 0.1f * v;
    out[((size_t)b * NFEAT + g * 8 + o) * HWP + y * WW + x] = v;
  }
}

// ---------------------------------------------------------------------------
// Offset/mask conv: 64 -> 216 channels, 3x3, dilation D, pad D. (unchanged R0)
// ---------------------------------------------------------------------------
template <int D>
__global__ __launch_bounds__(128) void omconv_kernel(
    const float* __restrict__ in, const float* __restrict__ wT,  // [(c*9+k)*216 + oc]
    const float* __restrict__ bias, float* __restrict__ out) {
  constexpr int TW2 = 32 + 2 * D, TH2 = 8 + 2 * D;
  const int tx = threadIdx.x, ty = threadIdx.y;
  const int bx = blockIdx.x * 32, by = blockIdx.y * 8;
  const int ob = (blockIdx.z % 9) * 24;
  const int b = blockIdx.z / 9;

  __shared__ float sIn[8 * TH2 * TW2];
  float acc0[24], acc1[24];
#pragma unroll
  for (int o = 0; o < 24; ++o) {
    acc0[o] = 0.f;
    acc1[o] = 0.f;
  }

  const int lid = ty * 16 + tx;
  for (int icc = 0; icc < 8; ++icc) {
    __syncthreads();
    for (int i = lid; i < 8 * TH2 * TW2; i += 128) {
      int xx = i % TW2;
      int r = i / TW2;
      int yy = r % TH2;
      int c = r / TH2;
      int gx = bx + xx - D, gy = by + yy - D;
      float v = 0.f;
      if (gx >= 0 && gx < WW && gy >= 0 && gy < HH)
        v = in[((size_t)b * NFEAT + icc * 8 + c) * HWP + gy * WW + gx];
      sIn[i] = v;
    }
    __syncthreads();
    for (int c = 0; c < 8; ++c) {
#pragma unroll
      for (int k = 0; k < 9; ++k) {
        const float* row = &sIn[(c * TH2 + ty + (k / 3) * D) * TW2 + tx + (k % 3) * D];
        float v0 = row[0], v1 = row[16];
        const float* wp = wT + ((icc * 8 + c) * 9 + k) * 216 + ob;  // uniform
#pragma unroll
        for (int o = 0; o < 24; ++o) {
          acc0[o] = fmaf(v0, wp[o], acc0[o]);
          acc1[o] = fmaf(v1, wp[o], acc1[o]);
        }
      }
    }
  }
  const int y = by + ty;
#pragma unroll
  for (int o = 0; o < 24; ++o) {
    float bsv = bias[ob + o];
    size_t basei = ((size_t)b * 216 + ob + o) * HWP + y * WW + bx + tx;
    out[basei] = acc0[o] + bsv;
    out[basei + 16] = acc1[o] + bsv;
  }
}

// ---------------------------------------------------------------------------
// Modulated deformable conv (DCNv2) v2.
//  - x is PIXEL-MAJOR (b, hw, 64): the 8 channels of a deformable group are
//    two contiguous float4s -> 8 vector loads per (dg,k) instead of 32 scalar.
//  - 16 out-channels per thread (4 slabs) -> 2304 waves = 9 waves/CU.
//  - Corner validity folded into bilinear weights.
// Block (16,8) = one pixel/thread; blockIdx.z = b*4 + slab.
// ---------------------------------------------------------------------------
template <int D, bool LRELU>
__global__ __launch_bounds__(128) void dcn_kernel(
    const float* __restrict__ xT,  // (b, hw, 64) pixel-major
    const float* __restrict__ om,  // (b, 216, hw) raw conv out
    const float* __restrict__ wT,  // [(c*9+k)*64 + oc]
    const float* __restrict__ bias, float* __restrict__ out) {
  const int tx = threadIdx.x, ty = threadIdx.y;
  const int xp = blockIdx.x * 16 + tx;
  const int yp = blockIdx.y * 8 + ty;
  const int slab = blockIdx.z & 3, b = blockIdx.z >> 2;
  const int ob = slab * 16;

  float acc[16];
#pragma unroll
  for (int o = 0; o < 16; ++o) acc[o] = 0.f;

  const size_t bOM = (size_t)b * 216 * HWP;
  const int pix = yp * WW + xp;
  const float* xb = xT + (size_t)b * HWP * NFEAT;

  for (int dg = 0; dg < 8; ++dg) {
#pragma unroll
    for (int k = 0; k < 9; ++k) {
      float dy = om[bOM + (size_t)(dg * 18 + 2 * k) * HWP + pix];
      float dxv = om[bOM + (size_t)(dg * 18 + 2 * k + 1) * HWP + pix];
      float mr = om[bOM + (size_t)(144 + dg * 9 + k) * HWP + pix];
      float m = 1.f / (1.f + __expf(-mr));
      float py = (float)(yp + (k / 3 - 1) * D) + dy;
      float px = (float)(xp + (k % 3 - 1) * D) + dxv;
      float y0f = floorf(py), x0f = floorf(px);
      float ly = py - y0f, lx = px - x0f;
      int y0 = (int)y0f, x0 = (int)x0f;
      int y1 = y0 + 1, x1 = x0 + 1;
      bool vy0 = (unsigned)y0 < (unsigned)HH, vy1 = (unsigned)y1 < (unsigned)HH;
      bool vx0 = (unsigned)x0 < (unsigned)WW, vx1 = (unsigned)x1 < (unsigned)WW;
      int cy0 = min(max(y0, 0), HH - 1), cy1 = min(max(y1, 0), HH - 1);
      int cx0 = min(max(x0, 0), WW - 1), cx1 = min(max(x1, 0), WW - 1);
      float w00 = (vy0 && vx0) ? (1.f - ly) * (1.f - lx) * m : 0.f;
      float w01 = (vy0 && vx1) ? (1.f - ly) * lx * m : 0.f;
      float w10 = (vy1 && vx0) ? ly * (1.f - lx) * m : 0.f;
      float w11 = (vy1 && vx1) ? ly * lx * m : 0.f;
      const float4* p00 = (const float4*)(xb + ((size_t)(cy0 * WW + cx0)) * NFEAT + dg * 8);
      const float4* p01 = (const float4*)(xb + ((size_t)(cy0 * WW + cx1)) * NFEAT + dg * 8);
      const float4* p10 = (const float4*)(xb + ((size_t)(cy1 * WW + cx0)) * NFEAT + dg * 8);
      const float4* p11 = (const float4*)(xb + ((size_t)(cy1 * WW + cx1)) * NFEAT + dg * 8);
#pragma unroll
      for (int cc = 0; cc < 2; ++cc) {
        float4 v00 = p00[cc], v01 = p01[cc], v10 = p10[cc], v11 = p11[cc];
        float vals[4];
        vals[0] = w00 * v00.x + w01 * v01.x + w10 * v10.x + w11 * v11.x;
        vals[1] = w00 * v00.y + w01 * v01.y + w10 * v10.y + w11 * v11.y;
        vals[2] = w00 * v00.z + w01 * v01.z + w10 * v10.z + w11 * v11.z;
        vals[3] = w00 * v00.w + w01 * v01.w + w10 * v10.w + w11 * v11.w;
#pragma unroll
        for (int j = 0; j < 4; ++j) {
          int c = cc * 4 + j;
          const float* wp = wT + ((dg * 8 + c) * 9 + k) * 64 + ob;  // uniform s_load
#pragma unroll
          for (int o = 0; o < 16; ++o) acc[o] = fmaf(vals[j], wp[o], acc[o]);
        }
      }
    }
  }
#pragma unroll
  for (int o = 0; o < 16; ++o) {
    float v = acc[o] + bias[ob + o];
    if (LRELU) v = (v >= 0.f) ? v : 0.1f * v;
    out[((size_t)b * NFEAT + ob + o) * HWP + pix] = v;
  }
}

// ---------------------------------------------------------------------------
extern "C" void kernel_launch(void* const* d_in, const int* in_sizes, int n_in,
                              void* d_out, int out_size, void* d_ws, size_t ws_size,
                              hipStream_t stream) {
  const float* nbr = (const float*)d_in[0];
  const float* ref = (const float*)d_in[1];
  auto f = [&](int i) { return (const float*)d_in[i]; };

  float* ws = (float*)d_ws;
  const size_t FSZ = (size_t)BATCH * NFEAT * HWP;   // 2,359,296 floats
  const size_t OMSZ = (size_t)BATCH * 216 * HWP;    // 7,962,624 floats
  float* bufA = ws;
  float* bufB = ws + FSZ;
  float* bufC = ws + 2 * FSZ;
  float* bufD = ws + 3 * FSZ;
  float* omB = ws + 4 * FSZ;
  float* wts = ws + 4 * FSZ + OMSZ;  // 737,280 floats of transposed weights
  // nbr transposed lives in d_out (dead before the final write);
  // feat transposed (cascade) reuses bufD (dead after l1 fc conv).
  float* nbrT = (float*)d_out;

  // ---- weight transpose prep ----
  static const int srcIdx[20] = {2, 4, 6, 8, 10, 12, 14, 18, 20, 16,
                                 22, 24, 26, 30, 32, 28, 34, 36, 38, 40};
  static const int ocnA[20] = {64, 64, 216, 64, 64, 64, 64, 216, 64, 64,
                               64, 64, 64, 216, 64, 64, 64, 64, 216, 64};
  static const int ickA[20] = {144, 72, 576, 576, 144, 144, 72, 576, 576, 144,
                               144, 144, 72, 576, 576, 144, 144, 72, 576, 576};
  PrepArgs pa;
  int base = 0;
  const float* wt[20];
  for (int t = 0; t < 20; ++t) {
    pa.src[t] = f(srcIdx[t]);
    pa.ocn[t] = ocnA[t];
    pa.ick[t] = ickA[t];
    pa.base[t] = base;
    wt[t] = wts + base;
    base += ocnA[t] * ickA[t];
  }
  pa.base[20] = base;  // 737,280
  prep_kernel<<<(base + 255) / 256, 256, 0, stream>>>(pa, wts);

  dim3 gcGrid(3, 12, BATCH * 8), gcBlk(32, 8);
  dim3 omGrid(3, 12, BATCH * 9), omBlk(16, 8);
  dim3 dcGrid(6, 12, BATCH * 4), dcBlk(16, 8);
  dim3 trGrid(HWP / 64, BATCH), trBlk(64, 4);

  transpose_kernel<<<trGrid, trBlk, 0, stream>>>(nbr, nbrT);

  // ---- level 3 (dilation 5) ----
  gconv_kernel<16, true, true><<<gcGrid, gcBlk, 0, stream>>>(nbr, ref, wt[0], f(3), bufA);
  gconv_kernel<8, true, false><<<gcGrid, gcBlk, 0, stream>>>(bufA, nullptr, wt[1], f(5), bufB);
  omconv_kernel<5><<<omGrid, omBlk, 0, stream>>>(bufB, wt[2], f(7), omB);
  dcn_kernel<5, true><<<dcGrid, dcBlk, 0, stream>>>(nbrT, omB, wt[3], f(9), bufC);
  // bufB = to (off_l3), bufC = tf (feat_l3)

  // ---- level 2 (dilation 3) ----
  gconv_kernel<16, true, true><<<gcGrid, gcBlk, 0, stream>>>(nbr, ref, wt[4], f(11), bufA);
  gconv_kernel<16, true, true><<<gcGrid, gcBlk, 0, stream>>>(bufA, bufB, wt[5], f(13), bufD);
  gconv_kernel<8, true, false><<<gcGrid, gcBlk, 0, stream>>>(bufD, nullptr, wt[6], f(15), bufA);
  omconv_kernel<3><<<omGrid, omBlk, 0, stream>>>(bufA, wt[7], f(19), omB);
  dcn_kernel<3, false><<<dcGrid, dcBlk, 0, stream>>>(nbrT, omB, wt[8], f(21), bufB);
  gconv_kernel<16, true, true><<<gcGrid, gcBlk, 0, stream>>>(bufB, bufC, wt[9], f(17), bufD);
  // bufA = to (off_l2), bufD = tf (feat_l2)

  // ---- level 1 (dilation 1) ----
  gconv_kernel<16, true, true><<<gcGrid, gcBlk, 0, stream>>>(nbr, ref, wt[10], f(23), bufB);
  gconv_kernel<16, true, true><<<gcGrid, gcBlk, 0, stream>>>(bufB, bufA, wt[11], f(25), bufC);
  gconv_kernel<8, true, false><<<gcGrid, gcBlk, 0, stream>>>(bufC, nullptr, wt[12], f(27), bufB);
  omconv_kernel<1><<<omGrid, omBlk, 0, stream>>>(bufB, wt[13], f(31), omB);
  dcn_kernel<1, false><<<dcGrid, dcBlk, 0, stream>>>(nbrT, omB, wt[14], f(33), bufC);
  gconv_kernel<16, false, true><<<gcGrid, gcBlk, 0, stream>>>(bufC, bufD, wt[15], f(29), bufA);
  // bufA = feat after l1 (no lrelu); nbrT (in d_out) now dead

  // ---- cascade (dilation 1) ----
  float* featT = bufD;  // bufD dead after l1 fc conv
  transpose_kernel<<<trGrid, trBlk, 0, stream>>>(bufA, featT);
  gconv_kernel<16, true, true><<<gcGrid, gcBlk, 0, stream>>>(bufA, ref, wt[16], f(35), bufB);
  gconv_kernel<8, true, false><<<gcGrid, gcBlk, 0, stream>>>(bufB, nullptr, wt[17], f(37), bufC);
  omconv_kernel<1><<<omGrid, omBlk, 0, stream>>>(bufC, wt[18], f(39), omB);
  dcn_kernel<1, true><<<dcGrid, dcBlk, 0, stream>>>(featT, omB, wt[19], f(41), (float*)d_out);
}

// Round 4
// 1285.850 us; speedup vs baseline: 1.8779x; 1.4249x over previous
//
#include <hip/hip_runtime.h>

#define BATCH 4
#define NFEAT 64
#define DGRP 8
#define HH 96
#define WW 96
#define HWP (HH*WW)

typedef short short8 __attribute__((ext_vector_type(8)));
typedef float f32x16 __attribute__((ext_vector_type(16)));

__device__ inline short f2bf(float f) {
  union { float f; unsigned u; } v; v.f = f;
  unsigned r = v.u + 0x7fff + ((v.u >> 16) & 1);
  return (short)(r >> 16);
}

// ---------------------------------------------------------------------------
// Weight prep (fp32 transposed, for gconv/dcn): [(ic*9+k)*OC + oc].
// ---------------------------------------------------------------------------
struct PrepArgs {
  const float* src[20];
  int ocn[20];
  int ick[20];
  int base[21];
};

__global__ __launch_bounds__(256) void prep_kernel(PrepArgs a, float* __restrict__ dst) {
  int gid = blockIdx.x * 256 + threadIdx.x;
  if (gid >= a.base[20]) return;
  int t = 0;
  while (gid >= a.base[t + 1]) ++t;
  int local = gid - a.base[t];
  int OC = a.ocn[t], ICK = a.ick[t];
  int ik = local / OC;
  int oc = local - ik * OC;
  dst[gid] = a.src[t][oc * ICK + ik];
}

// ---------------------------------------------------------------------------
// om-weight prep (bf16, MFMA A layout): dst[t][oc][p*64+c], oc padded to 256.
// src shape (216, 64, 3, 3): src[oc*576 + c*9 + p].
// ---------------------------------------------------------------------------
__global__ __launch_bounds__(256) void prep_om(
    const float* __restrict__ s0, const float* __restrict__ s1,
    const float* __restrict__ s2, const float* __restrict__ s3,
    short* __restrict__ dst) {
  int gid = blockIdx.x * 256 + threadIdx.x;
  if (gid >= 4 * 256 * 576) return;
  int t = gid / 147456, r = gid % 147456;
  int oc = r / 576, ck = r % 576;
  int p = ck >> 6, c = ck & 63;
  const float* s = (t == 0) ? s0 : (t == 1) ? s1 : (t == 2) ? s2 : s3;
  float v = (oc < 216) ? s[(size_t)oc * 576 + c * 9 + p] : 0.f;
  dst[gid] = f2bf(v);
}

// ---------------------------------------------------------------------------
// Channel-major (b,64,hw) -> pixel-major fp32 (b,hw,64) transpose (for DCN).
// ---------------------------------------------------------------------------
__global__ __launch_bounds__(256) void transpose_kernel(
    const float* __restrict__ in, float* __restrict__ out) {
  __shared__ float s[64][65];
  const int p0 = blockIdx.x * 64;
  const int b = blockIdx.y;
  const int tx = threadIdx.x, ty = threadIdx.y;
  for (int c = ty; c < 64; c += 4)
    s[c][tx] = in[((size_t)b * NFEAT + c) * HWP + p0 + tx];
  __syncthreads();
  for (int p = ty; p < 64; p += 4)
    out[((size_t)b * HWP + p0 + p) * NFEAT + tx] = s[tx][p];
}

// ---------------------------------------------------------------------------
// Grouped 3x3 conv, pad=1 dil=1, groups=8. OUT2: also write pixel-major bf16
// copy (feeds omconv_mfma's B operand).
// ---------------------------------------------------------------------------
template <int CPG, bool LRELU, bool INTERLEAVE, bool OUT2>
__global__ __launch_bounds__(256) void gconv_kernel(
    const float* __restrict__ in0, const float* __restrict__ in1,
    const float* __restrict__ wT,   // [(j*9+k)*64 + oc_global]
    const float* __restrict__ bias, float* __restrict__ out,
    short* __restrict__ out2) {
  const int tx = threadIdx.x, ty = threadIdx.y;
  const int bx = blockIdx.x * 32, by = blockIdx.y * 8;
  const int g = blockIdx.z & 7, b = blockIdx.z >> 3;

  __shared__ float sIn[CPG][10][34];
  const int lid = ty * 32 + tx;
  for (int i = lid; i < CPG * 340; i += 256) {
    int xx = i % 34;
    int r = i / 34;
    int yy = r % 10;
    int j = r / 10;
    int gx = bx + xx - 1, gy = by + yy - 1;
    float v = 0.f;
    if (gx >= 0 && gx < WW && gy >= 0 && gy < HH) {
      const float* src;
      int ch;
      if (INTERLEAVE) {
        src = (j & 1) ? in1 : in0;
        ch = g * (CPG / 2) + (j >> 1);
      } else {
        src = in0;
        ch = g * CPG + j;
      }
      v = src[((size_t)b * NFEAT + ch) * HWP + gy * WW + gx];
    }
    sIn[j][yy][xx] = v;
  }
  __syncthreads();

  float acc[8];
#pragma unroll
  for (int o = 0; o < 8; ++o) acc[o] = bias[g * 8 + o];

  for (int j = 0; j < CPG; ++j) {
#pragma unroll
    for (int k = 0; k < 9; ++k) {
      float v = sIn[j][ty + k / 3][tx + k % 3];
      const float* wp = wT + (j * 9 + k) * 64 + g * 8;  // uniform -> s_load
#pragma unroll
      for (int o = 0; o < 8; ++o) acc[o] = fmaf(v, wp[o], acc[o]);
    }
  }
  const int y = by + ty, x = bx + tx;
#pragma unroll
  for (int o = 0; o < 8; ++o) {
    float v = acc[o];
    if (LRELU) v = (v >= 0.f) ? v : 0.1f * v;
    acc[o] = v;
    out[((size_t)b * NFEAT + g * 8 + o) * HWP + y * WW + x] = v;
  }
  if (OUT2) {
    short8 pk;
#pragma unroll
    for (int o = 0; o < 8; ++o) pk[o] = f2bf(acc[o]);
    *(short8*)(out2 + ((size_t)b * HWP + y * WW + x) * 64 + g * 8) = pk;
  }
}

// ---------------------------------------------------------------------------
// Offset/mask conv 64->216 as implicit GEMM on MFMA (bf16 in, fp32 acc).
// C[oc][pix] = sum_{p,c} W[oc][p*64+c] * in[pix + shift(p)][c].
// Block (64,4) = 4 waves; each wave: oc tiles {w*32, 128+w*32} x 64 pixels
// (2x2 MFMAs of 32x32x16 per K-step). No LDS. Grid (144, BATCH).
// A frag: lane holds W[oc = m0+ (lane&31)][k0 + (lane>>5)*8 + j]  (16B load)
// B frag: lane holds in[pix(n0+(lane&31), shifted)][c0 + (lane>>5)*8 + j]
// C/D: col(n)=lane&31, row(m)=(r&3)+8*(r>>2)+4*(lane>>5).
// ---------------------------------------------------------------------------
template <int D>
__global__ __launch_bounds__(256) void omconv_mfma(
    const short* __restrict__ pixT,  // (b, hw, 64) bf16
    const short* __restrict__ Wbf,   // (256, 576) bf16, oc-padded
    const float* __restrict__ bias,  // (216)
    float* __restrict__ out) {       // (b, 216, hw) fp32
  const int lane = threadIdx.x;
  const int w = threadIdx.y;
  const int col = lane & 31, half = lane >> 5;
  const int n0 = blockIdx.x * 64;
  const int b = blockIdx.y;

  const int pix0 = n0 + col, pix1 = n0 + 32 + col;
  const int y0 = pix0 / WW, x0 = pix0 % WW;
  const int y1 = pix1 / WW, x1 = pix1 % WW;

  const short* aPtr0 = Wbf + (size_t)(w * 32 + col) * 576 + half * 8;
  const short* aPtr1 = Wbf + (size_t)(128 + w * 32 + col) * 576 + half * 8;
  const short* pixb = pixT + (size_t)b * HWP * 64 + half * 8;

  f32x16 acc00 = {}, acc01 = {}, acc10 = {}, acc11 = {};
  const short8 ZV = {0, 0, 0, 0, 0, 0, 0, 0};

  for (int p = 0; p < 9; ++p) {
    const int dy = (p / 3 - 1) * D, dx = (p % 3 - 1) * D;
    const int sy0 = y0 + dy, sx0 = x0 + dx;
    const int sy1 = y1 + dy, sx1 = x1 + dx;
    const bool v0 = ((unsigned)sy0 < (unsigned)HH) && ((unsigned)sx0 < (unsigned)WW);
    const bool v1 = ((unsigned)sy1 < (unsigned)HH) && ((unsigned)sx1 < (unsigned)WW);
    const int c0 = min(max(sy0, 0), HH - 1) * WW + min(max(sx0, 0), WW - 1);
    const int c1 = min(max(sy1, 0), HH - 1) * WW + min(max(sx1, 0), WW - 1);
    const short8* b0p = (const short8*)(pixb + (size_t)c0 * 64);
    const short8* b1p = (const short8*)(pixb + (size_t)c1 * 64);
    const short8* a0p = (const short8*)(aPtr0 + p * 64);
    const short8* a1p = (const short8*)(aPtr1 + p * 64);
#pragma unroll
    for (int q = 0; q < 4; ++q) {
      short8 A0 = a0p[2 * q], A1 = a1p[2 * q];
      short8 B0 = v0 ? b0p[2 * q] : ZV;
      short8 B1 = v1 ? b1p[2 * q] : ZV;
      acc00 = __builtin_amdgcn_mfma_f32_32x32x16_bf16(A0, B0, acc00, 0, 0, 0);
      acc01 = __builtin_amdgcn_mfma_f32_32x32x16_bf16(A0, B1, acc01, 0, 0, 0);
      acc10 = __builtin_amdgcn_mfma_f32_32x32x16_bf16(A1, B0, acc10, 0, 0, 0);
      acc11 = __builtin_amdgcn_mfma_f32_32x32x16_bf16(A1, B1, acc11, 0, 0, 0);
    }
  }

  const int ocb0 = w * 32, ocb1 = 128 + w * 32;
#pragma unroll
  for (int r = 0; r < 16; ++r) {
    const int rrow = (r & 3) + 8 * (r >> 2) + 4 * half;
    const int oc0 = ocb0 + rrow;         // <= 127, always valid
    const int oc1 = ocb1 + rrow;         // may be >= 216 (pad)
    const float bs0 = bias[oc0];
    out[((size_t)b * 216 + oc0) * HWP + pix0] = acc00[r] + bs0;
    out[((size_t)b * 216 + oc0) * HWP + pix1] = acc01[r] + bs0;
    if (oc1 < 216) {
      const float bs1 = bias[oc1];
      out[((size_t)b * 216 + oc1) * HWP + pix0] = acc10[r] + bs1;
      out[((size_t)b * 216 + oc1) * HWP + pix1] = acc11[r] + bs1;
    }
  }
}

// ---------------------------------------------------------------------------
// Modulated deformable conv (DCNv2), pixel-major fp32 x. (unchanged R1)
// ---------------------------------------------------------------------------
template <int D, bool LRELU>
__global__ __launch_bounds__(128) void dcn_kernel(
    const float* __restrict__ xT,  // (b, hw, 64) pixel-major
    const float* __restrict__ om,  // (b, 216, hw) raw conv out
    const float* __restrict__ wT,  // [(c*9+k)*64 + oc]
    const float* __restrict__ bias, float* __restrict__ out) {
  const int tx = threadIdx.x, ty = threadIdx.y;
  const int xp = blockIdx.x * 16 + tx;
  const int yp = blockIdx.y * 8 + ty;
  const int slab = blockIdx.z & 3, b = blockIdx.z >> 2;
  const int ob = slab * 16;

  float acc[16];
#pragma unroll
  for (int o = 0; o < 16; ++o) acc[o] = 0.f;

  const size_t bOM = (size_t)b * 216 * HWP;
  const int pix = yp * WW + xp;
  const float* xb = xT + (size_t)b * HWP * NFEAT;

  for (int dg = 0; dg < 8; ++dg) {
#pragma unroll
    for (int k = 0; k < 9; ++k) {
      float dy = om[bOM + (size_t)(dg * 18 + 2 * k) * HWP + pix];
      float dxv = om[bOM + (size_t)(dg * 18 + 2 * k + 1) * HWP + pix];
      float mr = om[bOM + (size_t)(144 + dg * 9 + k) * HWP + pix];
      float m = 1.f / (1.f + __expf(-mr));
      float py = (float)(yp + (k / 3 - 1) * D) + dy;
      float px = (float)(xp + (k % 3 - 1) * D) + dxv;
      float y0f = floorf(py), x0f = floorf(px);
      float ly = py - y0f, lx = px - x0f;
      int y0 = (int)y0f, x0 = (int)x0f;
      int y1 = y0 + 1, x1 = x0 + 1;
      bool vy0 = (unsigned)y0 < (unsigned)HH, vy1 = (unsigned)y1 < (unsigned)HH;
      bool vx0 = (unsigned)x0 < (unsigned)WW, vx1 = (unsigned)x1 < (unsigned)WW;
      int cy0 = min(max(y0, 0), HH - 1), cy1 = min(max(y1, 0), HH - 1);
      int cx0 = min(max(x0, 0), WW - 1), cx1 = min(max(x1, 0), WW - 1);
      float w00 = (vy0 && vx0) ? (1.f - ly) * (1.f - lx) * m : 0.f;
      float w01 = (vy0 && vx1) ? (1.f - ly) * lx * m : 0.f;
      float w10 = (vy1 && vx0) ? ly * (1.f - lx) * m : 0.f;
      float w11 = (vy1 && vx1) ? ly * lx * m : 0.f;
      const float4* p00 = (const float4*)(xb + ((size_t)(cy0 * WW + cx0)) * NFEAT + dg * 8);
      const float4* p01 = (const float4*)(xb + ((size_t)(cy0 * WW + cx1)) * NFEAT + dg * 8);
      const float4* p10 = (const float4*)(xb + ((size_t)(cy1 * WW + cx0)) * NFEAT + dg * 8);
      const float4* p11 = (const float4*)(xb + ((size_t)(cy1 * WW + cx1)) * NFEAT + dg * 8);
#pragma unroll
      for (int cc = 0; cc < 2; ++cc) {
        float4 v00 = p00[cc], v01 = p01[cc], v10 = p10[cc], v11 = p11[cc];
        float vals[4];
        vals[0] = w00 * v00.x + w01 * v01.x + w10 * v10.x + w11 * v11.x;
        vals[1] = w00 * v00.y + w01 * v01.y + w10 * v10.y + w11 * v11.y;
        vals[2] = w00 * v00.z + w01 * v01.z + w10 * v10.z + w11 * v11.z;
        vals[3] = w00 * v00.w + w01 * v01.w + w10 * v10.w + w11 * v11.w;
#pragma unroll
        for (int j = 0; j < 4; ++j) {
          int c = cc * 4 + j;
          const float* wp = wT + ((dg * 8 + c) * 9 + k) * 64 + ob;  // uniform s_load
#pragma unroll
          for (int o = 0; o < 16; ++o) acc[o] = fmaf(vals[j], wp[o], acc[o]);
        }
      }
    }
  }
#pragma unroll
  for (int o = 0; o < 16; ++o) {
    float v = acc[o] + bias[ob + o];
    if (LRELU) v = (v >= 0.f) ? v : 0.1f * v;
    out[((size_t)b * NFEAT + ob + o) * HWP + pix] = v;
  }
}

// ---------------------------------------------------------------------------
extern "C" void kernel_launch(void* const* d_in, const int* in_sizes, int n_in,
                              void* d_out, int out_size, void* d_ws, size_t ws_size,
                              hipStream_t stream) {
  const float* nbr = (const float*)d_in[0];
  const float* ref = (const float*)d_in[1];
  auto f = [&](int i) { return (const float*)d_in[i]; };

  float* ws = (float*)d_ws;
  const size_t FSZ = (size_t)BATCH * NFEAT * HWP;   // 2,359,296 floats
  const size_t OMSZ = (size_t)BATCH * 216 * HWP;    // 7,962,624 floats
  float* bufA = ws;
  float* bufB = ws + FSZ;
  float* bufC = ws + 2 * FSZ;
  float* bufD = ws + 3 * FSZ;
  float* omB = ws + 4 * FSZ;
  float* wts = ws + 4 * FSZ + OMSZ;                   // 737,280 floats
  short* wbf = (short*)(ws + 4 * FSZ + OMSZ + 737280);  // 589,824 bf16 (294,912 f)
  short* pixB = (short*)(ws + 4 * FSZ + OMSZ + 737280 + 294912);  // 2,359,296 bf16
  float* nbrT = (float*)d_out;  // dead before final write

  // ---- weight prep ----
  static const int srcIdx[20] = {2, 4, 6, 8, 10, 12, 14, 18, 20, 16,
                                 22, 24, 26, 30, 32, 28, 34, 36, 38, 40};
  static const int ocnA[20] = {64, 64, 216, 64, 64, 64, 64, 216, 64, 64,
                               64, 64, 64, 216, 64, 64, 64, 64, 216, 64};
  static const int ickA[20] = {144, 72, 576, 576, 144, 144, 72, 576, 576, 144,
                               144, 144, 72, 576, 576, 144, 144, 72, 576, 576};
  PrepArgs pa;
  int base = 0;
  const float* wt[20];
  for (int t = 0; t < 20; ++t) {
    pa.src[t] = f(srcIdx[t]);
    pa.ocn[t] = ocnA[t];
    pa.ick[t] = ickA[t];
    pa.base[t] = base;
    wt[t] = wts + base;
    base += ocnA[t] * ickA[t];
  }
  pa.base[20] = base;  // 737,280
  prep_kernel<<<(base + 255) / 256, 256, 0, stream>>>(pa, wts);
  prep_om<<<(4 * 147456 + 255) / 256, 256, 0, stream>>>(f(6), f(18), f(30), f(38), wbf);
  short* wbf_l3 = wbf;
  short* wbf_l2 = wbf + 147456;
  short* wbf_l1 = wbf + 2 * 147456;
  short* wbf_cas = wbf + 3 * 147456;

  dim3 gcGrid(3, 12, BATCH * 8), gcBlk(32, 8);
  dim3 omGrid(HWP / 64, BATCH), omBlk(64, 4);
  dim3 dcGrid(6, 12, BATCH * 4), dcBlk(16, 8);
  dim3 trGrid(HWP / 64, BATCH), trBlk(64, 4);

  transpose_kernel<<<trGrid, trBlk, 0, stream>>>(nbr, nbrT);

  // ---- level 3 (dilation 5) ----
  gconv_kernel<16, true, true, false><<<gcGrid, gcBlk, 0, stream>>>(nbr, ref, wt[0], f(3), bufA, nullptr);
  gconv_kernel<8, true, false, true><<<gcGrid, gcBlk, 0, stream>>>(bufA, nullptr, wt[1], f(5), bufB, pixB);
  omconv_mfma<5><<<omGrid, omBlk, 0, stream>>>(pixB, wbf_l3, f(7), omB);
  dcn_kernel<5, true><<<dcGrid, dcBlk, 0, stream>>>(nbrT, omB, wt[3], f(9), bufC);
  // bufB = to (off_l3), bufC = tf (feat_l3)

  // ---- level 2 (dilation 3) ----
  gconv_kernel<16, true, true, false><<<gcGrid, gcBlk, 0, stream>>>(nbr, ref, wt[4], f(11), bufA, nullptr);
  gconv_kernel<16, true, true, false><<<gcGrid, gcBlk, 0, stream>>>(bufA, bufB, wt[5], f(13), bufD, nullptr);
  gconv_kernel<8, true, false, true><<<gcGrid, gcBlk, 0, stream>>>(bufD, nullptr, wt[6], f(15), bufA, pixB);
  omconv_mfma<3><<<omGrid, omBlk, 0, stream>>>(pixB, wbf_l2, f(19), omB);
  dcn_kernel<3, false><<<dcGrid, dcBlk, 0, stream>>>(nbrT, omB, wt[8], f(21), bufB);
  gconv_kernel<16, true, true, false><<<gcGrid, gcBlk, 0, stream>>>(bufB, bufC, wt[9], f(17), bufD, nullptr);
  // bufA = to (off_l2), bufD = tf (feat_l2)

  // ---- level 1 (dilation 1) ----
  gconv_kernel<16, true, true, false><<<gcGrid, gcBlk, 0, stream>>>(nbr, ref, wt[10], f(23), bufB, nullptr);
  gconv_kernel<16, true, true, false><<<gcGrid, gcBlk, 0, stream>>>(bufB, bufA, wt[11], f(25), bufC, nullptr);
  gconv_kernel<8, true, false, true><<<gcGrid, gcBlk, 0, stream>>>(bufC, nullptr, wt[12], f(27), bufB, pixB);
  omconv_mfma<1><<<omGrid, omBlk, 0, stream>>>(pixB, wbf_l1, f(31), omB);
  dcn_kernel<1, false><<<dcGrid, dcBlk, 0, stream>>>(nbrT, omB, wt[14], f(33), bufC);
  gconv_kernel<16, false, true, false><<<gcGrid, gcBlk, 0, stream>>>(bufC, bufD, wt[15], f(29), bufA, nullptr);
  // bufA = feat after l1 (no lrelu); nbrT (in d_out) now dead

  // ---- cascade (dilation 1) ----
  float* featT = bufD;  // bufD dead after l1 fc conv
  transpose_kernel<<<trGrid, trBlk, 0, stream>>>(bufA, featT);
  gconv_kernel<16, true, true, false><<<gcGrid, gcBlk, 0, stream>>>(bufA, ref, wt[16], f(35), bufB, nullptr);
  gconv_kernel<8, true, false, true><<<gcGrid, gcBlk, 0, stream>>>(bufB, nullptr, wt[17], f(37), bufC, pixB);
  omconv_mfma<1><<<omGrid, omBlk, 0, stream>>>(pixB, wbf_cas, f(39), omB);
  dcn_kernel<1, true><<<dcGrid, dcBlk, 0, stream>>>(featT, omB, wt[19], f(41), (float*)d_out);
}

// Round 5
// 921.994 us; speedup vs baseline: 2.6190x; 1.3946x over previous
//
#include <hip/hip_runtime.h>

#define BATCH 4
#define NFEAT 64
#define DGRP 8
#define HH 96
#define WW 96
#define HWP (HH*WW)

typedef short short8 __attribute__((ext_vector_type(8)));
typedef float f32x16 __attribute__((ext_vector_type(16)));

__device__ inline short f2bf(float f) {
  union { float f; unsigned u; } v; v.f = f;
  unsigned r = v.u + 0x7fff + ((v.u >> 16) & 1);
  return (short)(r >> 16);
}
__device__ inline float bf2f(short s) {
  return __uint_as_float(((unsigned)(unsigned short)s) << 16);
}

// ---------------------------------------------------------------------------
// Weight prep (fp32 transposed, for gconv): [(ic*9+k)*OC + oc].
// ---------------------------------------------------------------------------
struct PrepArgs {
  const float* src[20];
  int ocn[20];
  int ick[20];
  int base[21];
};

__global__ __launch_bounds__(256) void prep_kernel(PrepArgs a, float* __restrict__ dst) {
  int gid = blockIdx.x * 256 + threadIdx.x;
  if (gid >= a.base[20]) return;
  int t = 0;
  while (gid >= a.base[t + 1]) ++t;
  int local = gid - a.base[t];
  int OC = a.ocn[t], ICK = a.ick[t];
  int ik = local / OC;
  int oc = local - ik * OC;
  dst[gid] = a.src[t][oc * ICK + ik];
}

// ---------------------------------------------------------------------------
// om-weight prep (bf16, MFMA A layout): dst[t][oc][p*64+c], oc padded to 256.
// src shape (216, 64, 3, 3): src[oc*576 + c*9 + p].
// ---------------------------------------------------------------------------
__global__ __launch_bounds__(256) void prep_om(
    const float* __restrict__ s0, const float* __restrict__ s1,
    const float* __restrict__ s2, const float* __restrict__ s3,
    short* __restrict__ dst) {
  int gid = blockIdx.x * 256 + threadIdx.x;
  if (gid >= 4 * 256 * 576) return;
  int t = gid / 147456, r = gid % 147456;
  int oc = r / 576, ck = r % 576;
  int p = ck >> 6, c = ck & 63;
  const float* s = (t == 0) ? s0 : (t == 1) ? s1 : (t == 2) ? s2 : s3;
  float v = (oc < 216) ? s[(size_t)oc * 576 + c * 9 + p] : 0.f;
  dst[gid] = f2bf(v);
}

// ---------------------------------------------------------------------------
// dcn-weight prep: (64,64,3,3) fp32 is already [oc][c*9+k] row-major ->
// straight bf16 convert. 4 tensors.
// ---------------------------------------------------------------------------
__global__ __launch_bounds__(256) void prep_dcnw(
    const float* __restrict__ s0, const float* __restrict__ s1,
    const float* __restrict__ s2, const float* __restrict__ s3,
    short* __restrict__ dst) {
  int gid = blockIdx.x * 256 + threadIdx.x;
  if (gid >= 4 * 36864) return;
  int t = gid / 36864, r = gid % 36864;
  const float* s = (t == 0) ? s0 : (t == 1) ? s1 : (t == 2) ? s2 : s3;
  dst[gid] = f2bf(s[r]);
}

// ---------------------------------------------------------------------------
// Channel-major (b,64,hw) fp32 -> pixel-major (b,hw,64) bf16 (DCN sampling x).
// ---------------------------------------------------------------------------
__global__ __launch_bounds__(256) void transpose_bf16(
    const float* __restrict__ in, short* __restrict__ out) {
  __shared__ float s[64][65];
  const int p0 = blockIdx.x * 64;
  const int b = blockIdx.y;
  const int tx = threadIdx.x, ty = threadIdx.y;
  for (int c = ty; c < 64; c += 4)
    s[c][tx] = in[((size_t)b * NFEAT + c) * HWP + p0 + tx];
  __syncthreads();
  for (int p = ty; p < 64; p += 4)
    out[((size_t)b * HWP + p0 + p) * NFEAT + tx] = f2bf(s[tx][p]);
}

// ---------------------------------------------------------------------------
// Grouped 3x3 conv, pad=1 dil=1, groups=8. OUT2: also write pixel-major bf16.
// ---------------------------------------------------------------------------
template <int CPG, bool LRELU, bool INTERLEAVE, bool OUT2>
__global__ __launch_bounds__(256) void gconv_kernel(
    const float* __restrict__ in0, const float* __restrict__ in1,
    const float* __restrict__ wT,   // [(j*9+k)*64 + oc_global]
    const float* __restrict__ bias, float* __restrict__ out,
    short* __restrict__ out2) {
  const int tx = threadIdx.x, ty = threadIdx.y;
  const int bx = blockIdx.x * 32, by = blockIdx.y * 8;
  const int g = blockIdx.z & 7, b = blockIdx.z >> 3;

  __shared__ float sIn[CPG][10][34];
  const int lid = ty * 32 + tx;
  for (int i = lid; i < CPG * 340; i += 256) {
    int xx = i % 34;
    int r = i / 34;
    int yy = r % 10;
    int j = r / 10;
    int gx = bx + xx - 1, gy = by + yy - 1;
    float v = 0.f;
    if (gx >= 0 && gx < WW && gy >= 0 && gy < HH) {
      const float* src;
      int ch;
      if (INTERLEAVE) {
        src = (j & 1) ? in1 : in0;
        ch = g * (CPG / 2) + (j >> 1);
      } else {
        src = in0;
        ch = g * CPG + j;
      }
      v = src[((size_t)b * NFEAT + ch) * HWP + gy * WW + gx];
    }
    sIn[j][yy][xx] = v;
  }
  __syncthreads();

  float acc[8];
#pragma unroll
  for (int o = 0; o < 8; ++o) acc[o] = bias[g * 8 + o];

  for (int j = 0; j < CPG; ++j) {
#pragma unroll
    for (int k = 0; k < 9; ++k) {
      float v = sIn[j][ty + k / 3][tx + k % 3];
      const float* wp = wT + (j * 9 + k) * 64 + g * 8;  // uniform -> s_load
#pragma unroll
      for (int o = 0; o < 8; ++o) acc[o] = fmaf(v, wp[o], acc[o]);
    }
  }
  const int y = by + ty, x = bx + tx;
#pragma unroll
  for (int o = 0; o < 8; ++o) {
    float v = acc[o];
    if (LRELU) v = (v >= 0.f) ? v : 0.1f * v;
    acc[o] = v;
    out[((size_t)b * NFEAT + g * 8 + o) * HWP + y * WW + x] = v;
  }
  if (OUT2) {
    short8 pk;
#pragma unroll
    for (int o = 0; o < 8; ++o) pk[o] = f2bf(acc[o]);
    *(short8*)(out2 + ((size_t)b * HWP + y * WW + x) * 64 + g * 8) = pk;
  }
}

// ---------------------------------------------------------------------------
// Offset/mask conv 64->216 as implicit GEMM on MFMA. (unchanged, proven R3)
// ---------------------------------------------------------------------------
template <int D>
__global__ __launch_bounds__(256) void omconv_mfma(
    const short* __restrict__ pixT,  // (b, hw, 64) bf16
    const short* __restrict__ Wbf,   // (256, 576) bf16, oc-padded
    const float* __restrict__ bias,  // (216)
    float* __restrict__ out) {       // (b, 216, hw) fp32
  const int lane = threadIdx.x;
  const int w = threadIdx.y;
  const int col = lane & 31, half = lane >> 5;
  const int n0 = blockIdx.x * 64;
  const int b = blockIdx.y;

  const int pix0 = n0 + col, pix1 = n0 + 32 + col;
  const int y0 = pix0 / WW, x0 = pix0 % WW;
  const int y1 = pix1 / WW, x1 = pix1 % WW;

  const short* aPtr0 = Wbf + (size_t)(w * 32 + col) * 576 + half * 8;
  const short* aPtr1 = Wbf + (size_t)(128 + w * 32 + col) * 576 + half * 8;
  const short* pixb = pixT + (size_t)b * HWP * 64 + half * 8;

  f32x16 acc00 = {}, acc01 = {}, acc10 = {}, acc11 = {};
  const short8 ZV = {0, 0, 0, 0, 0, 0, 0, 0};

  for (int p = 0; p < 9; ++p) {
    const int dy = (p / 3 - 1) * D, dx = (p % 3 - 1) * D;
    const int sy0 = y0 + dy, sx0 = x0 + dx;
    const int sy1 = y1 + dy, sx1 = x1 + dx;
    const bool v0 = ((unsigned)sy0 < (unsigned)HH) && ((unsigned)sx0 < (unsigned)WW);
    const bool v1 = ((unsigned)sy1 < (unsigned)HH) && ((unsigned)sx1 < (unsigned)WW);
    const int c0 = min(max(sy0, 0), HH - 1) * WW + min(max(sx0, 0), WW - 1);
    const int c1 = min(max(sy1, 0), HH - 1) * WW + min(max(sx1, 0), WW - 1);
    const short8* b0p = (const short8*)(pixb + (size_t)c0 * 64);
    const short8* b1p = (const short8*)(pixb + (size_t)c1 * 64);
    const short8* a0p = (const short8*)(aPtr0 + p * 64);
    const short8* a1p = (const short8*)(aPtr1 + p * 64);
#pragma unroll
    for (int q = 0; q < 4; ++q) {
      short8 A0 = a0p[2 * q], A1 = a1p[2 * q];
      short8 B0 = v0 ? b0p[2 * q] : ZV;
      short8 B1 = v1 ? b1p[2 * q] : ZV;
      acc00 = __builtin_amdgcn_mfma_f32_32x32x16_bf16(A0, B0, acc00, 0, 0, 0);
      acc01 = __builtin_amdgcn_mfma_f32_32x32x16_bf16(A0, B1, acc01, 0, 0, 0);
      acc10 = __builtin_amdgcn_mfma_f32_32x32x16_bf16(A1, B0, acc10, 0, 0, 0);
      acc11 = __builtin_amdgcn_mfma_f32_32x32x16_bf16(A1, B1, acc11, 0, 0, 0);
    }
  }

  const int ocb0 = w * 32, ocb1 = 128 + w * 32;
#pragma unroll
  for (int r = 0; r < 16; ++r) {
    const int rrow = (r & 3) + 8 * (r >> 2) + 4 * half;
    const int oc0 = ocb0 + rrow;
    const int oc1 = ocb1 + rrow;
    const float bs0 = bias[oc0];
    out[((size_t)b * 216 + oc0) * HWP + pix0] = acc00[r] + bs0;
    out[((size_t)b * 216 + oc0) * HWP + pix1] = acc01[r] + bs0;
    if (oc1 < 216) {
      const float bs1 = bias[oc1];
      out[((size_t)b * 216 + oc1) * HWP + pix0] = acc10[r] + bs1;
      out[((size_t)b * 216 + oc1) * HWP + pix1] = acc11[r] + bs1;
    }
  }
}

// ---------------------------------------------------------------------------
// DCN stage 1: bilinear sampling -> S[b][pix][576] bf16.
// Thread = (pix, dg) x2 (ty covers dg, dg+4). x is bf16 pixel-major: the 8
// channels of a dg at one corner = one 16B short8 load (4 loads per tap).
// Block (64,4), grid (144, BATCH).
// ---------------------------------------------------------------------------
template <int D>
__global__ __launch_bounds__(256) void dcn_sample(
    const short* __restrict__ xT,   // (b, hw, 64) bf16 pixel-major
    const float* __restrict__ om,   // (b, 216, hw) fp32 raw
    short* __restrict__ S) {        // (b, hw, 576) bf16
  const int tx = threadIdx.x, ty = threadIdx.y;
  const int pix = blockIdx.x * 64 + tx;
  const int b = blockIdx.y;
  const int yp = pix / WW, xp = pix % WW;
  const size_t bOM = (size_t)b * 216 * HWP;
  const short* xb = xT + (size_t)b * HWP * 64;
  short* Sp = S + ((size_t)b * HWP + pix) * 576;

  for (int dgi = 0; dgi < 2; ++dgi) {
    const int dg = ty + dgi * 4;
    float vals[72];
#pragma unroll
    for (int k = 0; k < 9; ++k) {
      float dy = om[bOM + (size_t)(dg * 18 + 2 * k) * HWP + pix];
      float dxv = om[bOM + (size_t)(dg * 18 + 2 * k + 1) * HWP + pix];
      float mr = om[bOM + (size_t)(144 + dg * 9 + k) * HWP + pix];
      float m = 1.f / (1.f + __expf(-mr));
      float py = (float)(yp + (k / 3 - 1) * D) + dy;
      float px = (float)(xp + (k % 3 - 1) * D) + dxv;
      float y0f = floorf(py), x0f = floorf(px);
      float ly = py - y0f, lx = px - x0f;
      int y0 = (int)y0f, x0 = (int)x0f;
      int y1 = y0 + 1, x1 = x0 + 1;
      bool vy0 = (unsigned)y0 < (unsigned)HH, vy1 = (unsigned)y1 < (unsigned)HH;
      bool vx0 = (unsigned)x0 < (unsigned)WW, vx1 = (unsigned)x1 < (unsigned)WW;
      int cy0 = min(max(y0, 0), HH - 1), cy1 = min(max(y1, 0), HH - 1);
      int cx0 = min(max(x0, 0), WW - 1), cx1 = min(max(x1, 0), WW - 1);
      float w00 = (vy0 && vx0) ? (1.f - ly) * (1.f - lx) * m : 0.f;
      float w01 = (vy0 && vx1) ? (1.f - ly) * lx * m : 0.f;
      float w10 = (vy1 && vx0) ? ly * (1.f - lx) * m : 0.f;
      float w11 = (vy1 && vx1) ? ly * lx * m : 0.f;
      short8 s00 = *(const short8*)(xb + (size_t)(cy0 * WW + cx0) * 64 + dg * 8);
      short8 s01 = *(const short8*)(xb + (size_t)(cy0 * WW + cx1) * 64 + dg * 8);
      short8 s10 = *(const short8*)(xb + (size_t)(cy1 * WW + cx0) * 64 + dg * 8);
      short8 s11 = *(const short8*)(xb + (size_t)(cy1 * WW + cx1) * 64 + dg * 8);
#pragma unroll
      for (int cl = 0; cl < 8; ++cl) {
        vals[cl * 9 + k] = w00 * bf2f(s00[cl]) + w01 * bf2f(s01[cl]) +
                           w10 * bf2f(s10[cl]) + w11 * bf2f(s11[cl]);
      }
    }
    short* dst = Sp + dg * 72;
#pragma unroll
    for (int g = 0; g < 9; ++g) {
      short8 pk;
#pragma unroll
      for (int j = 0; j < 8; ++j) pk[j] = f2bf(vals[g * 8 + j]);
      *(short8*)(dst + g * 8) = pk;
    }
  }
}

// ---------------------------------------------------------------------------
// DCN stage 2: GEMM out[oc][pix] = sum_k S[pix][k]*Wd[oc][k] + bias, K=576.
// Same proven fragment scheme as omconv_mfma. Block (64,4): wave w covers
// oc tile (w&1)*32, pix tile (w>>1)*32. Grid (144, BATCH).
// ---------------------------------------------------------------------------
template <bool LRELU>
__global__ __launch_bounds__(256) void dcn_gemm(
    const short* __restrict__ S,    // (b, hw, 576) bf16
    const short* __restrict__ Wd,   // (64, 576) bf16
    const float* __restrict__ bias, // (64)
    float* __restrict__ out) {      // (b, 64, hw) fp32
  const int lane = threadIdx.x;
  const int w = threadIdx.y;
  const int col = lane & 31, half = lane >> 5;
  const int n0 = blockIdx.x * 64;
  const int b = blockIdx.y;
  const int ocb = (w & 1) * 32;
  const int pixt = n0 + (w >> 1) * 32 + col;

  const short* aPtr = Wd + (size_t)(ocb + col) * 576 + half * 8;
  const short* bPtr = S + ((size_t)b * HWP + pixt) * 576 + half * 8;

  f32x16 acc = {};
#pragma unroll
  for (int kk = 0; kk < 36; ++kk) {
    short8 A = *(const short8*)(aPtr + kk * 16);
    short8 B = *(const short8*)(bPtr + kk * 16);
    acc = __builtin_amdgcn_mfma_f32_32x32x16_bf16(A, B, acc, 0, 0, 0);
  }
#pragma unroll
  for (int r = 0; r < 16; ++r) {
    const int rrow = (r & 3) + 8 * (r >> 2) + 4 * half;
    const int oc = ocb + rrow;
    float v = acc[r] + bias[oc];
    if (LRELU) v = (v >= 0.f) ? v : 0.1f * v;
    out[((size_t)b * NFEAT + oc) * HWP + pixt] = v;
  }
}

// ---------------------------------------------------------------------------
extern "C" void kernel_launch(void* const* d_in, const int* in_sizes, int n_in,
                              void* d_out, int out_size, void* d_ws, size_t ws_size,
                              hipStream_t stream) {
  const float* nbr = (const float*)d_in[0];
  const float* ref = (const float*)d_in[1];
  auto f = [&](int i) { return (const float*)d_in[i]; };

  float* ws = (float*)d_ws;
  const size_t FSZ = (size_t)BATCH * NFEAT * HWP;   // 2,359,296 floats
  const size_t OMSZ = (size_t)BATCH * 216 * HWP;    // 7,962,624 floats
  float* bufA = ws;
  float* bufB = ws + FSZ;
  float* bufC = ws + 2 * FSZ;
  float* bufD = ws + 3 * FSZ;
  float* omB = ws + 4 * FSZ;
  float* wts = ws + 4 * FSZ + OMSZ;                      // 737,280 floats
  short* wbf = (short*)(wts + 737280);                   // 589,824 shorts
  short* pixB = (short*)(wts + 737280 + 294912);         // 2,359,296 shorts
  short* wdcn = (short*)(wts + 737280 + 294912 + 1179648);  // 147,456 shorts
  short* Sbuf = (short*)(wts + 737280 + 294912 + 1179648 + 73728);  // 21,233,664 shorts
  short* nbrT16 = (short*)d_out;  // (b,hw,64) bf16, dead before final write

  // ---- weight prep ----
  static const int srcIdx[20] = {2, 4, 6, 8, 10, 12, 14, 18, 20, 16,
                                 22, 24, 26, 30, 32, 28, 34, 36, 38, 40};
  static const int ocnA[20] = {64, 64, 216, 64, 64, 64, 64, 216, 64, 64,
                               64, 64, 64, 216, 64, 64, 64, 64, 216, 64};
  static const int ickA[20] = {144, 72, 576, 576, 144, 144, 72, 576, 576, 144,
                               144, 144, 72, 576, 576, 144, 144, 72, 576, 576};
  PrepArgs pa;
  int base = 0;
  const float* wt[20];
  for (int t = 0; t < 20; ++t) {
    pa.src[t] = f(srcIdx[t]);
    pa.ocn[t] = ocnA[t];
    pa.ick[t] = ickA[t];
    pa.base[t] = base;
    wt[t] = wts + base;
    base += ocnA[t] * ickA[t];
  }
  pa.base[20] = base;  // 737,280
  prep_kernel<<<(base + 255) / 256, 256, 0, stream>>>(pa, wts);
  prep_om<<<(4 * 147456 + 255) / 256, 256, 0, stream>>>(f(6), f(18), f(30), f(38), wbf);
  prep_dcnw<<<(4 * 36864 + 255) / 256, 256, 0, stream>>>(f(8), f(20), f(32), f(40), wdcn);
  short* wbf_l3 = wbf;
  short* wbf_l2 = wbf + 147456;
  short* wbf_l1 = wbf + 2 * 147456;
  short* wbf_cas = wbf + 3 * 147456;
  short* wd_l3 = wdcn;
  short* wd_l2 = wdcn + 36864;
  short* wd_l1 = wdcn + 2 * 36864;
  short* wd_cas = wdcn + 3 * 36864;

  dim3 gcGrid(3, 12, BATCH * 8), gcBlk(32, 8);
  dim3 omGrid(HWP / 64, BATCH), omBlk(64, 4);
  dim3 smGrid(HWP / 64, BATCH), smBlk(64, 4);
  dim3 dgGrid(HWP / 64, BATCH), dgBlk(64, 4);
  dim3 trGrid(HWP / 64, BATCH), trBlk(64, 4);

  transpose_bf16<<<trGrid, trBlk, 0, stream>>>(nbr, nbrT16);

  // ---- level 3 (dilation 5) ----
  gconv_kernel<16, true, true, false><<<gcGrid, gcBlk, 0, stream>>>(nbr, ref, wt[0], f(3), bufA, nullptr);
  gconv_kernel<8, true, false, true><<<gcGrid, gcBlk, 0, stream>>>(bufA, nullptr, wt[1], f(5), bufB, pixB);
  omconv_mfma<5><<<omGrid, omBlk, 0, stream>>>(pixB, wbf_l3, f(7), omB);
  dcn_sample<5><<<smGrid, smBlk, 0, stream>>>(nbrT16, omB, Sbuf);
  dcn_gemm<true><<<dgGrid, dgBlk, 0, stream>>>(Sbuf, wd_l3, f(9), bufC);
  // bufB = to (off_l3), bufC = tf (feat_l3)

  // ---- level 2 (dilation 3) ----
  gconv_kernel<16, true, true, false><<<gcGrid, gcBlk, 0, stream>>>(nbr, ref, wt[4], f(11), bufA, nullptr);
  gconv_kernel<16, true, true, false><<<gcGrid, gcBlk, 0, stream>>>(bufA, bufB, wt[5], f(13), bufD, nullptr);
  gconv_kernel<8, true, false, true><<<gcGrid, gcBlk, 0, stream>>>(bufD, nullptr, wt[6], f(15), bufA, pixB);
  omconv_mfma<3><<<omGrid, omBlk, 0, stream>>>(pixB, wbf_l2, f(19), omB);
  dcn_sample<3><<<smGrid, smBlk, 0, stream>>>(nbrT16, omB, Sbuf);
  dcn_gemm<false><<<dgGrid, dgBlk, 0, stream>>>(Sbuf, wd_l2, f(21), bufB);
  gconv_kernel<16, true, true, false><<<gcGrid, gcBlk, 0, stream>>>(bufB, bufC, wt[9], f(17), bufD, nullptr);
  // bufA = to (off_l2), bufD = tf (feat_l2)

  // ---- level 1 (dilation 1) ----
  gconv_kernel<16, true, true, false><<<gcGrid, gcBlk, 0, stream>>>(nbr, ref, wt[10], f(23), bufB, nullptr);
  gconv_kernel<16, true, true, false><<<gcGrid, gcBlk, 0, stream>>>(bufB, bufA, wt[11], f(25), bufC, nullptr);
  gconv_kernel<8, true, false, true><<<gcGrid, gcBlk, 0, stream>>>(bufC, nullptr, wt[12], f(27), bufB, pixB);
  omconv_mfma<1><<<omGrid, omBlk, 0, stream>>>(pixB, wbf_l1, f(31), omB);
  dcn_sample<1><<<smGrid, smBlk, 0, stream>>>(nbrT16, omB, Sbuf);
  dcn_gemm<false><<<dgGrid, dgBlk, 0, stream>>>(Sbuf, wd_l1, f(33), bufC);
  gconv_kernel<16, false, true, false><<<gcGrid, gcBlk, 0, stream>>>(bufC, bufD, wt[15], f(29), bufA, nullptr);
  // bufA = feat after l1 (no lrelu); nbrT16 (in d_out) now dead

  // ---- cascade (dilation 1) ----
  short* featT16 = (short*)bufD;  // bufD dead after l1 fc conv
  transpose_bf16<<<trGrid, trBlk, 0, stream>>>(bufA, featT16);
  gconv_kernel<16, true, true, false><<<gcGrid, gcBlk, 0, stream>>>(bufA, ref, wt[16], f(35), bufB, nullptr);
  gconv_kernel<8, true, false, true><<<gcGrid, gcBlk, 0, stream>>>(bufB, nullptr, wt[17], f(37), bufC, pixB);
  omconv_mfma<1><<<omGrid, omBlk, 0, stream>>>(pixB, wbf_cas, f(39), omB);
  dcn_sample<1><<<smGrid, smBlk, 0, stream>>>(featT16, omB, Sbuf);
  dcn_gemm<true><<<dgGrid, dgBlk, 0, stream>>>(Sbuf, wd_cas, f(41), (float*)d_out);
}

// Round 6
// 917.319 us; speedup vs baseline: 2.6324x; 1.0051x over previous
//
#include <hip/hip_runtime.h>

#define BATCH 4
#define NFEAT 64
#define DGRP 8
#define HH 96
#define WW 96
#define HWP (HH*WW)

typedef short short8 __attribute__((ext_vector_type(8)));
typedef float f32x16 __attribute__((ext_vector_type(16)));

__device__ inline short f2bf(float f) {
  union { float f; unsigned u; } v; v.f = f;
  unsigned r = v.u + 0x7fff + ((v.u >> 16) & 1);
  return (short)(r >> 16);
}
__device__ inline float bf2f(short s) {
  return __uint_as_float(((unsigned)(unsigned short)s) << 16);
}

// ---------------------------------------------------------------------------
// Weight prep (fp32 transposed, for gconv): [(ic*9+k)*OC + oc].
// ---------------------------------------------------------------------------
struct PrepArgs {
  const float* src[20];
  int ocn[20];
  int ick[20];
  int base[21];
};

__global__ __launch_bounds__(256) void prep_kernel(PrepArgs a, float* __restrict__ dst) {
  int gid = blockIdx.x * 256 + threadIdx.x;
  if (gid >= a.base[20]) return;
  int t = 0;
  while (gid >= a.base[t + 1]) ++t;
  int local = gid - a.base[t];
  int OC = a.ocn[t], ICK = a.ick[t];
  int ik = local / OC;
  int oc = local - ik * OC;
  dst[gid] = a.src[t][oc * ICK + ik];
}

// ---------------------------------------------------------------------------
// om-weight prep (bf16, MFMA A layout): dst[t][oc][p*64+c], oc padded to 256.
// src (216,64,3,3): src[oc*576 + c*9 + p].
// ---------------------------------------------------------------------------
__global__ __launch_bounds__(256) void prep_om(
    const float* __restrict__ s0, const float* __restrict__ s1,
    const float* __restrict__ s2, const float* __restrict__ s3,
    short* __restrict__ dst) {
  int gid = blockIdx.x * 256 + threadIdx.x;
  if (gid >= 4 * 256 * 576) return;
  int t = gid / 147456, r = gid % 147456;
  int oc = r / 576, ck = r % 576;
  int p = ck >> 6, c = ck & 63;
  const float* s = (t == 0) ? s0 : (t == 1) ? s1 : (t == 2) ? s2 : s3;
  float v = (oc < 216) ? s[(size_t)oc * 576 + c * 9 + p] : 0.f;
  dst[gid] = f2bf(v);
}

// ---------------------------------------------------------------------------
// dcn-weight prep (bf16): dst[t][oc][k*64+c] from src[oc*576 + c*9 + k].
// K-order (k*64+c) so sampling can emit one short8 per (tap, dg).
// ---------------------------------------------------------------------------
__global__ __launch_bounds__(256) void prep_dcnw(
    const float* __restrict__ s0, const float* __restrict__ s1,
    const float* __restrict__ s2, const float* __restrict__ s3,
    short* __restrict__ dst) {
  int gid = blockIdx.x * 256 + threadIdx.x;
  if (gid >= 4 * 36864) return;
  int t = gid / 36864, r = gid % 36864;
  int oc = r / 576, kc = r % 576;
  int k = kc >> 6, c = kc & 63;
  const float* s = (t == 0) ? s0 : (t == 1) ? s1 : (t == 2) ? s2 : s3;
  dst[gid] = f2bf(s[(size_t)oc * 576 + c * 9 + k]);
}

// ---------------------------------------------------------------------------
// Channel-major (b,64,hw) fp32 -> pixel-major (b,hw,64) bf16.
// ---------------------------------------------------------------------------
__global__ __launch_bounds__(256) void transpose_bf16(
    const float* __restrict__ in, short* __restrict__ out) {
  __shared__ float s[64][65];
  const int p0 = blockIdx.x * 64;
  const int b = blockIdx.y;
  const int tx = threadIdx.x, ty = threadIdx.y;
  for (int c = ty; c < 64; c += 4)
    s[c][tx] = in[((size_t)b * NFEAT + c) * HWP + p0 + tx];
  __syncthreads();
  for (int p = ty; p < 64; p += 4)
    out[((size_t)b * HWP + p0 + p) * NFEAT + tx] = f2bf(s[tx][p]);
}

// ---------------------------------------------------------------------------
// Grouped 3x3 conv, pad=1 dil=1, groups=8. OUT2: also write pixel-major bf16.
// ---------------------------------------------------------------------------
template <int CPG, bool LRELU, bool INTERLEAVE, bool OUT2>
__global__ __launch_bounds__(256) void gconv_kernel(
    const float* __restrict__ in0, const float* __restrict__ in1,
    const float* __restrict__ wT,   // [(j*9+k)*64 + oc_global]
    const float* __restrict__ bias, float* __restrict__ out,
    short* __restrict__ out2) {
  const int tx = threadIdx.x, ty = threadIdx.y;
  const int bx = blockIdx.x * 32, by = blockIdx.y * 8;
  const int g = blockIdx.z & 7, b = blockIdx.z >> 3;

  __shared__ float sIn[CPG][10][34];
  const int lid = ty * 32 + tx;
  for (int i = lid; i < CPG * 340; i += 256) {
    int xx = i % 34;
    int r = i / 34;
    int yy = r % 10;
    int j = r / 10;
    int gx = bx + xx - 1, gy = by + yy - 1;
    float v = 0.f;
    if (gx >= 0 && gx < WW && gy >= 0 && gy < HH) {
      const float* src;
      int ch;
      if (INTERLEAVE) {
        src = (j & 1) ? in1 : in0;
        ch = g * (CPG / 2) + (j >> 1);
      } else {
        src = in0;
        ch = g * CPG + j;
      }
      v = src[((size_t)b * NFEAT + ch) * HWP + gy * WW + gx];
    }
    sIn[j][yy][xx] = v;
  }
  __syncthreads();

  float acc[8];
#pragma unroll
  for (int o = 0; o < 8; ++o) acc[o] = bias[g * 8 + o];

  for (int j = 0; j < CPG; ++j) {
#pragma unroll
    for (int k = 0; k < 9; ++k) {
      float v = sIn[j][ty + k / 3][tx + k % 3];
      const float* wp = wT + (j * 9 + k) * 64 + g * 8;  // uniform -> s_load
#pragma unroll
      for (int o = 0; o < 8; ++o) acc[o] = fmaf(v, wp[o], acc[o]);
    }
  }
  const int y = by + ty, x = bx + tx;
#pragma unroll
  for (int o = 0; o < 8; ++o) {
    float v = acc[o];
    if (LRELU) v = (v >= 0.f) ? v : 0.1f * v;
    acc[o] = v;
    out[((size_t)b * NFEAT + g * 8 + o) * HWP + y * WW + x] = v;
  }
  if (OUT2) {
    short8 pk;
#pragma unroll
    for (int o = 0; o < 8; ++o) pk[o] = f2bf(acc[o]);
    *(short8*)(out2 + ((size_t)b * HWP + y * WW + x) * 64 + g * 8) = pk;
  }
}

// ---------------------------------------------------------------------------
// Offset/mask conv v2: one 32x32 MFMA tile per wave, depth-2 prefetch.
// Grid (288, 2, BATCH), block (64,4). Wave -> oc tile = blockIdx.y*4 + w
// (tile 7 is all-pad -> early exit). 9216-wave dispatch for latency hiding.
// ---------------------------------------------------------------------------
template <int D>
__global__ __launch_bounds__(256) void omconv_mfma(
    const short* __restrict__ pixT,  // (b, hw, 64) bf16
    const short* __restrict__ Wbf,   // (256, 576) [oc][p*64+c]
    const float* __restrict__ bias,  // (216)
    float* __restrict__ out) {       // (b, 216, hw) fp32
  const int lane = threadIdx.x;
  const int w = threadIdx.y;
  const int col = lane & 31, half = lane >> 5;
  const int tile = blockIdx.y * 4 + w;
  if (tile == 7) return;             // pad rows 224..255, nothing to do
  const int pix = blockIdx.x * 32 + col;
  const int b = blockIdx.z;
  const int yp = pix / WW, xp = pix % WW;

  int cs[9];
#pragma unroll
  for (int p = 0; p < 9; ++p) {
    int sy = yp + (p / 3 - 1) * D, sx = xp + (p % 3 - 1) * D;
    bool v = ((unsigned)sy < (unsigned)HH) && ((unsigned)sx < (unsigned)WW);
    cs[p] = v ? (sy * WW + sx) : -1;
  }
  const short* aP = Wbf + (size_t)(tile * 32 + col) * 576 + half * 8;
  const short* bP = pixT + (size_t)b * HWP * 64 + half * 8;
  const short8 ZV = {0, 0, 0, 0, 0, 0, 0, 0};

  auto ldA = [&](int kk) { return *(const short8*)(aP + kk * 16); };
  auto ldB = [&](int kk) {
    int c = cs[kk >> 2];
    return (c >= 0) ? *(const short8*)(bP + (size_t)c * 64 + (kk & 3) * 16) : ZV;
  };

  f32x16 acc = {};
  short8 A0 = ldA(0), B0 = ldB(0);
  short8 A1 = ldA(1), B1 = ldB(1);
#pragma unroll
  for (int kk = 0; kk < 36; ++kk) {
    short8 A2 = A1, B2 = B1;
    if (kk + 2 < 36) { A2 = ldA(kk + 2); B2 = ldB(kk + 2); }
    acc = __builtin_amdgcn_mfma_f32_32x32x16_bf16(A0, B0, acc, 0, 0, 0);
    A0 = A1; B0 = B1; A1 = A2; B1 = B2;
  }

  const int ocb = tile * 32;
#pragma unroll
  for (int r = 0; r < 16; ++r) {
    int oc = ocb + (r & 3) + 8 * (r >> 2) + 4 * half;
    if (oc < 216)
      out[((size_t)b * 216 + oc) * HWP + pix] = acc[r] + bias[oc];
  }
}

// ---------------------------------------------------------------------------
// DCN stage 1: bilinear sampling -> S[b][pix][k*64 + dg*8 + cl] bf16.
// Thread = (pix-in-32, dg). One contiguous short8 store per tap.
// Grid (288, BATCH), block (32, 8) -> 4608 waves.
// ---------------------------------------------------------------------------
template <int D>
__global__ __launch_bounds__(256) void dcn_sample(
    const short* __restrict__ xT,   // (b, hw, 64) bf16 pixel-major
    const float* __restrict__ om,   // (b, 216, hw) fp32 raw
    short* __restrict__ S) {        // (b, hw, 576)
  const int px = threadIdx.x;       // 0..31
  const int dg = threadIdx.y;       // 0..7
  const int pix = blockIdx.x * 32 + px;
  const int b = blockIdx.y;
  const int yp = pix / WW, xp = pix % WW;
  const size_t bOM = (size_t)b * 216 * HWP;
  const short* xb = xT + (size_t)b * HWP * 64 + dg * 8;
  short* Sp = S + ((size_t)b * HWP + pix) * 576 + dg * 8;

#pragma unroll
  for (int k = 0; k < 9; ++k) {
    float dy = om[bOM + (size_t)(dg * 18 + 2 * k) * HWP + pix];
    float dxv = om[bOM + (size_t)(dg * 18 + 2 * k + 1) * HWP + pix];
    float mr = om[bOM + (size_t)(144 + dg * 9 + k) * HWP + pix];
    float m = 1.f / (1.f + __expf(-mr));
    float py = (float)(yp + (k / 3 - 1) * D) + dy;
    float px_ = (float)(xp + (k % 3 - 1) * D) + dxv;
    float y0f = floorf(py), x0f = floorf(px_);
    float ly = py - y0f, lx = px_ - x0f;
    int y0 = (int)y0f, x0 = (int)x0f;
    int y1 = y0 + 1, x1 = x0 + 1;
    bool vy0 = (unsigned)y0 < (unsigned)HH, vy1 = (unsigned)y1 < (unsigned)HH;
    bool vx0 = (unsigned)x0 < (unsigned)WW, vx1 = (unsigned)x1 < (unsigned)WW;
    int cy0 = min(max(y0, 0), HH - 1), cy1 = min(max(y1, 0), HH - 1);
    int cx0 = min(max(x0, 0), WW - 1), cx1 = min(max(x1, 0), WW - 1);
    float w00 = (vy0 && vx0) ? (1.f - ly) * (1.f - lx) * m : 0.f;
    float w01 = (vy0 && vx1) ? (1.f - ly) * lx * m : 0.f;
    float w10 = (vy1 && vx0) ? ly * (1.f - lx) * m : 0.f;
    float w11 = (vy1 && vx1) ? ly * lx * m : 0.f;
    short8 s00 = *(const short8*)(xb + (size_t)(cy0 * WW + cx0) * 64);
    short8 s01 = *(const short8*)(xb + (size_t)(cy0 * WW + cx1) * 64);
    short8 s10 = *(const short8*)(xb + (size_t)(cy1 * WW + cx0) * 64);
    short8 s11 = *(const short8*)(xb + (size_t)(cy1 * WW + cx1) * 64);
    short8 pk;
#pragma unroll
    for (int cl = 0; cl < 8; ++cl) {
      float v = w00 * bf2f(s00[cl]) + w01 * bf2f(s01[cl]) +
                w10 * bf2f(s10[cl]) + w11 * bf2f(s11[cl]);
      pk[cl] = f2bf(v);
    }
    *(short8*)(Sp + k * 64) = pk;
  }
}

// ---------------------------------------------------------------------------
// DCN stage 2: GEMM out[oc][pix] = sum_k S[pix][k]*Wd[oc][k], K=576.
// K-split x2: wave w -> (octile = w&1, khalf = w>>1), 18 MFMAs each,
// LDS reduction (padded, conflict-free). Grid (288, BATCH), block (64,4).
// ---------------------------------------------------------------------------
template <bool LRELU>
__global__ __launch_bounds__(256) void dcn_gemm(
    const short* __restrict__ S,    // (b, hw, 576) bf16
    const short* __restrict__ Wd,   // (64, 576) bf16 [oc][k*64+c]
    const float* __restrict__ bias, // (64)
    float* __restrict__ out) {      // (b, 64, hw) fp32
  const int lane = threadIdx.x;
  const int w = threadIdx.y;
  const int col = lane & 31, half = lane >> 5;
  const int octile = w & 1, kh = w >> 1;
  const int pix = blockIdx.x * 32 + col;
  const int b = blockIdx.y;

  const short* aP = Wd + (size_t)(octile * 32 + col) * 576 + kh * 288 + half * 8;
  const short* bP = S + ((size_t)b * HWP + pix) * 576 + kh * 288 + half * 8;

  f32x16 acc = {};
  short8 A0 = *(const short8*)(aP), B0 = *(const short8*)(bP);
  short8 A1 = *(const short8*)(aP + 16), B1 = *(const short8*)(bP + 16);
#pragma unroll
  for (int kk = 0; kk < 18; ++kk) {
    short8 A2 = A1, B2 = B1;
    if (kk + 2 < 18) {
      A2 = *(const short8*)(aP + (kk + 2) * 16);
      B2 = *(const short8*)(bP + (kk + 2) * 16);
    }
    acc = __builtin_amdgcn_mfma_f32_32x32x16_bf16(A0, B0, acc, 0, 0, 0);
    A0 = A1; B0 = B1; A1 = A2; B1 = B2;
  }

  __shared__ float red[2][64][17];
  if (kh == 1) {
#pragma unroll
    for (int r = 0; r < 16; ++r) red[octile][lane][r] = acc[r];
  }
  __syncthreads();
  if (kh == 0) {
#pragma unroll
    for (int r = 0; r < 16; ++r) {
      const int oc = octile * 32 + (r & 3) + 8 * (r >> 2) + 4 * half;
      float v = acc[r] + red[octile][lane][r] + bias[oc];
      if (LRELU) v = (v >= 0.f) ? v : 0.1f * v;
      out[((size_t)b * NFEAT + oc) * HWP + pix] = v;
    }
  }
}

// ---------------------------------------------------------------------------
extern "C" void kernel_launch(void* const* d_in, const int* in_sizes, int n_in,
                              void* d_out, int out_size, void* d_ws, size_t ws_size,
                              hipStream_t stream) {
  const float* nbr = (const float*)d_in[0];
  const float* ref = (const float*)d_in[1];
  auto f = [&](int i) { return (const float*)d_in[i]; };

  float* ws = (float*)d_ws;
  const size_t FSZ = (size_t)BATCH * NFEAT * HWP;   // 2,359,296 floats
  const size_t OMSZ = (size_t)BATCH * 216 * HWP;    // 7,962,624 floats
  float* bufA = ws;
  float* bufB = ws + FSZ;
  float* bufC = ws + 2 * FSZ;
  float* bufD = ws + 3 * FSZ;
  float* omB = ws + 4 * FSZ;
  float* wts = ws + 4 * FSZ + OMSZ;                      // 737,280 floats
  short* wbf = (short*)(wts + 737280);                   // 589,824 shorts
  short* pixB = (short*)(wts + 737280 + 294912);         // 2,359,296 shorts
  short* wdcn = (short*)(wts + 737280 + 294912 + 1179648);  // 147,456 shorts
  short* Sbuf = (short*)(wts + 737280 + 294912 + 1179648 + 73728);  // 21,233,664 shorts
  short* nbrT16 = (short*)d_out;  // (b,hw,64) bf16, dead before final write

  // ---- weight prep ----
  static const int srcIdx[20] = {2, 4, 6, 8, 10, 12, 14, 18, 20, 16,
                                 22, 24, 26, 30, 32, 28, 34, 36, 38, 40};
  static const int ocnA[20] = {64, 64, 216, 64, 64, 64, 64, 216, 64, 64,
                               64, 64, 64, 216, 64, 64, 64, 64, 216, 64};
  static const int ickA[20] = {144, 72, 576, 576, 144, 144, 72, 576, 576, 144,
                               144, 144, 72, 576, 576, 144, 144, 72, 576, 576};
  PrepArgs pa;
  int base = 0;
  const float* wt[20];
  for (int t = 0; t < 20; ++t) {
    pa.src[t] = f(srcIdx[t]);
    pa.ocn[t] = ocnA[t];
    pa.ick[t] = ickA[t];
    pa.base[t] = base;
    wt[t] = wts + base;
    base += ocnA[t] * ickA[t];
  }
  pa.base[20] = base;  // 737,280
  prep_kernel<<<(base + 255) / 256, 256, 0, stream>>>(pa, wts);
  prep_om<<<(4 * 147456 + 255) / 256, 256, 0, stream>>>(f(6), f(18), f(30), f(38), wbf);
  prep_dcnw<<<(4 * 36864 + 255) / 256, 256, 0, stream>>>(f(8), f(20), f(32), f(40), wdcn);
  short* wbf_l3 = wbf;
  short* wbf_l2 = wbf + 147456;
  short* wbf_l1 = wbf + 2 * 147456;
  short* wbf_cas = wbf + 3 * 147456;
  short* wd_l3 = wdcn;
  short* wd_l2 = wdcn + 36864;
  short* wd_l1 = wdcn + 2 * 36864;
  short* wd_cas = wdcn + 3 * 36864;

  dim3 gcGrid(3, 12, BATCH * 8), gcBlk(32, 8);
  dim3 omGrid(288, 2, BATCH), omBlk(64, 4);
  dim3 smGrid(288, BATCH), smBlk(32, 8);
  dim3 dgGrid(288, BATCH), dgBlk(64, 4);
  dim3 trGrid(HWP / 64, BATCH), trBlk(64, 4);

  transpose_bf16<<<trGrid, trBlk, 0, stream>>>(nbr, nbrT16);

  // ---- level 3 (dilation 5) ----
  gconv_kernel<16, true, true, false><<<gcGrid, gcBlk, 0, stream>>>(nbr, ref, wt[0], f(3), bufA, nullptr);
  gconv_kernel<8, true, false, true><<<gcGrid, gcBlk, 0, stream>>>(bufA, nullptr, wt[1], f(5), bufB, pixB);
  omconv_mfma<5><<<omGrid, omBlk, 0, stream>>>(pixB, wbf_l3, f(7), omB);
  dcn_sample<5><<<smGrid, smBlk, 0, stream>>>(nbrT16, omB, Sbuf);
  dcn_gemm<true><<<dgGrid, dgBlk, 0, stream>>>(Sbuf, wd_l3, f(9), bufC);
  // bufB = to (off_l3), bufC = tf (feat_l3)

  // ---- level 2 (dilation 3) ----
  gconv_kernel<16, true, true, false><<<gcGrid, gcBlk, 0, stream>>>(nbr, ref, wt[4], f(11), bufA, nullptr);
  gconv_kernel<16, true, true, false><<<gcGrid, gcBlk, 0, stream>>>(bufA, bufB, wt[5], f(13), bufD, nullptr);
  gconv_kernel<8, true, false, true><<<gcGrid, gcBlk, 0, stream>>>(bufD, nullptr, wt[6], f(15), bufA, pixB);
  omconv_mfma<3><<<omGrid, omBlk, 0, stream>>>(pixB, wbf_l2, f(19), omB);
  dcn_sample<3><<<smGrid, smBlk, 0, stream>>>(nbrT16, omB, Sbuf);
  dcn_gemm<false><<<dgGrid, dgBlk, 0, stream>>>(Sbuf, wd_l2, f(21), bufB);
  gconv_kernel<16, true, true, false><<<gcGrid, gcBlk, 0, stream>>>(bufB, bufC, wt[9], f(17), bufD, nullptr);
  // bufA = to (off_l2), bufD = tf (feat_l2)

  // ---- level 1 (dilation 1) ----
  gconv_kernel<16, true, true, false><<<gcGrid, gcBlk, 0, stream>>>(nbr, ref, wt[10], f(23), bufB, nullptr);
  gconv_kernel<16, true, true, false><<<gcGrid, gcBlk, 0, stream>>>(bufB, bufA, wt[11], f(25), bufC, nullptr);
  gconv_kernel<8, true, false, true><<<gcGrid, gcBlk, 0, stream>>>(bufC, nullptr, wt[12], f(27), bufB, pixB);
  omconv_mfma<1><<<omGrid, omBlk, 0, stream>>>(pixB, wbf_l1, f(31), omB);
  dcn_sample<1><<<smGrid, smBlk, 0, stream>>>(nbrT16, omB, Sbuf);
  dcn_gemm<false><<<dgGrid, dgBlk, 0, stream>>>(Sbuf, wd_l1, f(33), bufC);
  gconv_kernel<16, false, true, false><<<gcGrid, gcBlk, 0, stream>>>(bufC, bufD, wt[15], f(29), bufA, nullptr);
  // bufA = feat after l1 (no lrelu); nbrT16 (in d_out) now dead

  // ---- cascade (dilation 1) ----
  short* featT16 = (short*)bufD;  // bufD dead after l1 fc conv
  transpose_bf16<<<trGrid, trBlk, 0, stream>>>(bufA, featT16);
  gconv_kernel<16, true, true, false><<<gcGrid, gcBlk, 0, stream>>>(bufA, ref, wt[16], f(35), bufB, nullptr);
  gconv_kernel<8, true, false, true><<<gcGrid, gcBlk, 0, stream>>>(bufB, nullptr, wt[17], f(37), bufC, pixB);
  omconv_mfma<1><<<omGrid, omBlk, 0, stream>>>(pixB, wbf_cas, f(39), omB);
  dcn_sample<1><<<smGrid, smBlk, 0, stream>>>(featT16, omB, Sbuf);
  dcn_gemm<true><<<dgGrid, dgBlk, 0, stream>>>(Sbuf, wd_cas, f(41), (float*)d_out);
}

// Round 7
// 647.448 us; speedup vs baseline: 3.7296x; 1.4168x over previous
//
#include <hip/hip_runtime.h>

#define BATCH 4
#define NFEAT 64
#define DGRP 8
#define HH 96
#define WW 96
#define HWP (HH*WW)

typedef short short4a __attribute__((ext_vector_type(4)));
typedef short short8 __attribute__((ext_vector_type(8)));
typedef float f32x16 __attribute__((ext_vector_type(16)));

__device__ inline short f2bf(float f) {
  union { float f; unsigned u; } v; v.f = f;
  unsigned r = v.u + 0x7fff + ((v.u >> 16) & 1);
  return (short)(r >> 16);
}
__device__ inline float bf2f(short s) {
  return __uint_as_float(((unsigned)(unsigned short)s) << 16);
}

// ---------------------------------------------------------------------------
// Weight prep (fp32 transposed, for gconv): [(ic*9+k)*OC + oc].
// ---------------------------------------------------------------------------
struct PrepArgs {
  const float* src[20];
  int ocn[20];
  int ick[20];
  int base[21];
};

__global__ __launch_bounds__(256) void prep_kernel(PrepArgs a, float* __restrict__ dst) {
  int gid = blockIdx.x * 256 + threadIdx.x;
  if (gid >= a.base[20]) return;
  int t = 0;
  while (gid >= a.base[t + 1]) ++t;
  int local = gid - a.base[t];
  int OC = a.ocn[t], ICK = a.ick[t];
  int ik = local / OC;
  int oc = local - ik * OC;
  dst[gid] = a.src[t][oc * ICK + ik];
}

// ---------------------------------------------------------------------------
// om-weight prep, MFMA-A-fragment-shuffled:
// dst[t][tile(8)][kk(36)][lane(64)][j(8)], lane=(half<<5)|col,
// value = W[oc=tile*32+col][k=kk*16+half*8+j], k = p*64+c, src[oc*576+c*9+p].
// A wave-load of one (tile,kk) fragment = contiguous 1KB.
// ---------------------------------------------------------------------------
__global__ __launch_bounds__(256) void prep_om(
    const float* __restrict__ s0, const float* __restrict__ s1,
    const float* __restrict__ s2, const float* __restrict__ s3,
    short* __restrict__ dst) {
  int gid = blockIdx.x * 256 + threadIdx.x;
  if (gid >= 4 * 147456) return;
  int t = gid / 147456, r = gid % 147456;
  int tile = r / 18432, r2 = r % 18432;
  int kk = r2 / 512, r3 = r2 % 512;
  int lane = r3 / 8, j = r3 % 8;
  int col = lane & 31, half = lane >> 5;
  int oc = tile * 32 + col;
  int k = kk * 16 + half * 8 + j;
  int p = k >> 6, c = k & 63;
  const float* s = (t == 0) ? s0 : (t == 1) ? s1 : (t == 2) ? s2 : s3;
  float v = (oc < 216) ? s[(size_t)oc * 576 + c * 9 + p] : 0.f;
  dst[gid] = f2bf(v);
}

// ---------------------------------------------------------------------------
// dcn-weight prep, same A-fragment shuffle: dst[t][tile(2)][kk(36)][lane][8].
// ---------------------------------------------------------------------------
__global__ __launch_bounds__(256) void prep_dcnw(
    const float* __restrict__ s0, const float* __restrict__ s1,
    const float* __restrict__ s2, const float* __restrict__ s3,
    short* __restrict__ dst) {
  int gid = blockIdx.x * 256 + threadIdx.x;
  if (gid >= 4 * 36864) return;
  int t = gid / 36864, r = gid % 36864;
  int tile = r / 18432, r2 = r % 18432;
  int kk = r2 / 512, r3 = r2 % 512;
  int lane = r3 / 8, j = r3 % 8;
  int col = lane & 31, half = lane >> 5;
  int oc = tile * 32 + col;
  int k = kk * 16 + half * 8 + j;
  int p = k >> 6, c = k & 63;
  const float* s = (t == 0) ? s0 : (t == 1) ? s1 : (t == 2) ? s2 : s3;
  dst[gid] = f2bf(s[(size_t)oc * 576 + c * 9 + p]);
}

// ---------------------------------------------------------------------------
// Channel-major (b,64,hw) fp32 -> pixel-major (b,hw,64) bf16.
// ---------------------------------------------------------------------------
__global__ __launch_bounds__(256) void transpose_bf16(
    const float* __restrict__ in, short* __restrict__ out) {
  __shared__ float s[64][65];
  const int p0 = blockIdx.x * 64;
  const int b = blockIdx.y;
  const int tx = threadIdx.x, ty = threadIdx.y;
  for (int c = ty; c < 64; c += 4)
    s[c][tx] = in[((size_t)b * NFEAT + c) * HWP + p0 + tx];
  __syncthreads();
  for (int p = ty; p < 64; p += 4)
    out[((size_t)b * HWP + p0 + p) * NFEAT + tx] = f2bf(s[tx][p]);
}

// ---------------------------------------------------------------------------
// Grouped 3x3 conv, pad=1 dil=1, groups=8. OUT2: also write pixel-major bf16.
// ---------------------------------------------------------------------------
template <int CPG, bool LRELU, bool INTERLEAVE, bool OUT2>
__global__ __launch_bounds__(256) void gconv_kernel(
    const float* __restrict__ in0, const float* __restrict__ in1,
    const float* __restrict__ wT,   // [(j*9+k)*64 + oc_global]
    const float* __restrict__ bias, float* __restrict__ out,
    short* __restrict__ out2) {
  const int tx = threadIdx.x, ty = threadIdx.y;
  const int bx = blockIdx.x * 32, by = blockIdx.y * 8;
  const int g = blockIdx.z & 7, b = blockIdx.z >> 3;

  __shared__ float sIn[CPG][10][34];
  const int lid = ty * 32 + tx;
  for (int i = lid; i < CPG * 340; i += 256) {
    int xx = i % 34;
    int r = i / 34;
    int yy = r % 10;
    int j = r / 10;
    int gx = bx + xx - 1, gy = by + yy - 1;
    float v = 0.f;
    if (gx >= 0 && gx < WW && gy >= 0 && gy < HH) {
      const float* src;
      int ch;
      if (INTERLEAVE) {
        src = (j & 1) ? in1 : in0;
        ch = g * (CPG / 2) + (j >> 1);
      } else {
        src = in0;
        ch = g * CPG + j;
      }
      v = src[((size_t)b * NFEAT + ch) * HWP + gy * WW + gx];
    }
    sIn[j][yy][xx] = v;
  }
  __syncthreads();

  float acc[8];
#pragma unroll
  for (int o = 0; o < 8; ++o) acc[o] = bias[g * 8 + o];

  for (int j = 0; j < CPG; ++j) {
#pragma unroll
    for (int k = 0; k < 9; ++k) {
      float v = sIn[j][ty + k / 3][tx + k % 3];
      const float* wp = wT + (j * 9 + k) * 64 + g * 8;  // uniform -> s_load
#pragma unroll
      for (int o = 0; o < 8; ++o) acc[o] = fmaf(v, wp[o], acc[o]);
    }
  }
  const int y = by + ty, x = bx + tx;
#pragma unroll
  for (int o = 0; o < 8; ++o) {
    float v = acc[o];
    if (LRELU) v = (v >= 0.f) ? v : 0.1f * v;
    acc[o] = v;
    out[((size_t)b * NFEAT + g * 8 + o) * HWP + y * WW + x] = v;
  }
  if (OUT2) {
    short8 pk;
#pragma unroll
    for (int o = 0; o < 8; ++o) pk[o] = f2bf(acc[o]);
    *(short8*)(out2 + ((size_t)b * HWP + y * WW + x) * 64 + g * 8) = pk;
  }
}

// ---------------------------------------------------------------------------
// Offset/mask conv v3: LDS-staged B, coalesced shuffled A, 2x2 blocking.
// Block (64,4) = 4 waves, 64 pixels, 8 oc-tiles (wave w -> tiles {w, w+4}).
// K staged in 2 phases (taps 0-4, 5-8) to stay under 64KB static LDS.
// Grid (144, BATCH).
// ---------------------------------------------------------------------------
#define BPITCH 324  // shorts per row: 5 taps * 64 + 4 pad; words/row=162 == 2 mod 32
template <int D>
__global__ __launch_bounds__(256) void omconv_mfma(
    const short* __restrict__ pixT,  // (b, hw, 64) bf16
    const short* __restrict__ Wsh,   // shuffled [tile(8)][kk(36)][lane][8]
    const float* __restrict__ bias,  // (216)
    float* __restrict__ out) {       // (b, 216, hw) fp32
  const int lane = threadIdx.x;
  const int w = threadIdx.y;
  const int lid = w * 64 + lane;
  const int col = lane & 31, half = lane >> 5;
  const int pixbase = blockIdx.x * 64;
  const int b = blockIdx.y;

  __shared__ short Bs[64 * BPITCH];  // 41,472 B

  const short* aP0 = Wsh + ((size_t)(w * 36) * 64) * 8 + (size_t)lane * 8;
  const short* aP1 = Wsh + ((size_t)((w + 4) * 36) * 64) * 8 + (size_t)lane * 8;
  const short* pixb = pixT + (size_t)b * HWP * 64;

  f32x16 acc00 = {}, acc01 = {}, acc10 = {}, acc11 = {};

  for (int ph = 0; ph < 2; ++ph) {
    const int ntap = ph ? 4 : 5, pbase = ph ? 5 : 0, kbase = ph ? 20 : 0;
    if (ph) __syncthreads();  // WAR before re-staging
    const int nchunk = 64 * ntap * 8;
    for (int i = lid; i < nchunk; i += 256) {
      int row = i / (ntap * 8), q = i % (ntap * 8);
      int p = pbase + (q >> 3), c8 = q & 7;
      int pix = pixbase + row;
      int yp = pix / WW, xp = pix % WW;
      int sy = yp + (p / 3 - 1) * D, sx = xp + (p % 3 - 1) * D;
      short4a lo = {0, 0, 0, 0}, hi = {0, 0, 0, 0};
      if (((unsigned)sy < (unsigned)HH) && ((unsigned)sx < (unsigned)WW)) {
        const short* src = pixb + (size_t)(sy * WW + sx) * 64 + c8 * 8;
        lo = *(const short4a*)src;
        hi = *(const short4a*)(src + 4);
      }
      short* dst = Bs + row * BPITCH + q * 8;
      *(short4a*)dst = lo;
      *(short4a*)(dst + 4) = hi;
    }
    __syncthreads();

    const int nkk = ntap * 4;
#pragma unroll 4
    for (int kk = 0; kk < nkk; ++kk) {
      const int kkg = kbase + kk;
      short8 A0 = *(const short8*)(aP0 + (size_t)kkg * 512);
      short8 A1 = *(const short8*)(aP1 + (size_t)kkg * 512);
      const short* b0 = Bs + col * BPITCH + kk * 16 + half * 8;
      const short* b1 = Bs + (32 + col) * BPITCH + kk * 16 + half * 8;
      short4a l0 = *(const short4a*)b0, h0 = *(const short4a*)(b0 + 4);
      short4a l1 = *(const short4a*)b1, h1 = *(const short4a*)(b1 + 4);
      short8 B0 = {l0[0], l0[1], l0[2], l0[3], h0[0], h0[1], h0[2], h0[3]};
      short8 B1 = {l1[0], l1[1], l1[2], l1[3], h1[0], h1[1], h1[2], h1[3]};
      acc00 = __builtin_amdgcn_mfma_f32_32x32x16_bf16(A0, B0, acc00, 0, 0, 0);
      acc01 = __builtin_amdgcn_mfma_f32_32x32x16_bf16(A0, B1, acc01, 0, 0, 0);
      acc10 = __builtin_amdgcn_mfma_f32_32x32x16_bf16(A1, B0, acc10, 0, 0, 0);
      acc11 = __builtin_amdgcn_mfma_f32_32x32x16_bf16(A1, B1, acc11, 0, 0, 0);
    }
  }

  const int pix0 = pixbase + col, pix1 = pixbase + 32 + col;
#pragma unroll
  for (int r = 0; r < 16; ++r) {
    const int rrow = (r & 3) + 8 * (r >> 2) + 4 * half;
    const int oc0 = w * 32 + rrow;          // tiles 0..3: always < 216
    const int oc1 = (w + 4) * 32 + rrow;    // tiles 4..7: may be pad
    const float bs0 = bias[oc0];
    out[((size_t)b * 216 + oc0) * HWP + pix0] = acc00[r] + bs0;
    out[((size_t)b * 216 + oc0) * HWP + pix1] = acc01[r] + bs0;
    if (oc1 < 216) {
      const float bs1 = bias[oc1];
      out[((size_t)b * 216 + oc1) * HWP + pix0] = acc10[r] + bs1;
      out[((size_t)b * 216 + oc1) * HWP + pix1] = acc11[r] + bs1;
    }
  }
}

// ---------------------------------------------------------------------------
// DCN stage 1: bilinear sampling -> S in B-FRAGMENT order:
// S[(b*288+pb)*36 + kk][lane][8] where kk = p*4+(dg>>1), lane = (dg&1)*32+px.
// Thread = (px in 32, dg). Grid (288, BATCH), block (32, 8).
// ---------------------------------------------------------------------------
template <int D>
__global__ __launch_bounds__(256) void dcn_sample(
    const short* __restrict__ xT,   // (b, hw, 64) bf16 pixel-major
    const float* __restrict__ om,   // (b, 216, hw) fp32 raw
    short* __restrict__ S) {
  const int px = threadIdx.x;       // 0..31
  const int dg = threadIdx.y;       // 0..7
  const int pb = blockIdx.x;
  const int b = blockIdx.y;
  const int pix = pb * 32 + px;
  const int yp = pix / WW, xp = pix % WW;
  const size_t bOM = (size_t)b * 216 * HWP;
  const short* xb = xT + (size_t)b * HWP * 64 + dg * 8;
  const int lane = (dg & 1) * 32 + px;
  short* Sp = S + (((size_t)(b * 288 + pb) * 36) * 64 + lane) * 8;

#pragma unroll
  for (int k = 0; k < 9; ++k) {
    float dy = om[bOM + (size_t)(dg * 18 + 2 * k) * HWP + pix];
    float dxv = om[bOM + (size_t)(dg * 18 + 2 * k + 1) * HWP + pix];
    float mr = om[bOM + (size_t)(144 + dg * 9 + k) * HWP + pix];
    float m = 1.f / (1.f + __expf(-mr));
    float py = (float)(yp + (k / 3 - 1) * D) + dy;
    float px_ = (float)(xp + (k % 3 - 1) * D) + dxv;
    float y0f = floorf(py), x0f = floorf(px_);
    float ly = py - y0f, lx = px_ - x0f;
    int y0 = (int)y0f, x0 = (int)x0f;
    int y1 = y0 + 1, x1 = x0 + 1;
    bool vy0 = (unsigned)y0 < (unsigned)HH, vy1 = (unsigned)y1 < (unsigned)HH;
    bool vx0 = (unsigned)x0 < (unsigned)WW, vx1 = (unsigned)x1 < (unsigned)WW;
    int cy0 = min(max(y0, 0), HH - 1), cy1 = min(max(y1, 0), HH - 1);
    int cx0 = min(max(x0, 0), WW - 1), cx1 = min(max(x1, 0), WW - 1);
    float w00 = (vy0 && vx0) ? (1.f - ly) * (1.f - lx) * m : 0.f;
    float w01 = (vy0 && vx1) ? (1.f - ly) * lx * m : 0.f;
    float w10 = (vy1 && vx0) ? ly * (1.f - lx) * m : 0.f;
    float w11 = (vy1 && vx1) ? ly * lx * m : 0.f;
    short8 s00 = *(const short8*)(xb + (size_t)(cy0 * WW + cx0) * 64);
    short8 s01 = *(const short8*)(xb + (size_t)(cy0 * WW + cx1) * 64);
    short8 s10 = *(const short8*)(xb + (size_t)(cy1 * WW + cx0) * 64);
    short8 s11 = *(const short8*)(xb + (size_t)(cy1 * WW + cx1) * 64);
    short8 pk;
#pragma unroll
    for (int cl = 0; cl < 8; ++cl) {
      float v = w00 * bf2f(s00[cl]) + w01 * bf2f(s01[cl]) +
                w10 * bf2f(s10[cl]) + w11 * bf2f(s11[cl]);
      pk[cl] = f2bf(v);
    }
    const int kk = k * 4 + (dg >> 1);
    *(short8*)(Sp + (size_t)kk * 512) = pk;
  }
}

// ---------------------------------------------------------------------------
// DCN stage 2: GEMM, both operands pre-shuffled -> all loads coalesced 1KB.
// K-split x2 + LDS reduction. Grid (288, BATCH), block (64,4).
// ---------------------------------------------------------------------------
template <bool LRELU>
__global__ __launch_bounds__(256) void dcn_gemm(
    const short* __restrict__ S,    // fragment-ordered (see dcn_sample)
    const short* __restrict__ Wd,   // shuffled [tile(2)][kk(36)][lane][8]
    const float* __restrict__ bias, // (64)
    float* __restrict__ out) {      // (b, 64, hw) fp32
  const int lane = threadIdx.x;
  const int w = threadIdx.y;
  const int col = lane & 31, half = lane >> 5;
  const int octile = w & 1, kh = w >> 1;
  const int pb = blockIdx.x;
  const int b = blockIdx.y;
  const int pix = pb * 32 + col;

  const short* aP = Wd + ((size_t)(octile * 36) * 64 + lane) * 8;
  const short* bP = S + (((size_t)(b * 288 + pb) * 36) * 64 + lane) * 8;

  f32x16 acc = {};
#pragma unroll 6
  for (int kk = 0; kk < 18; ++kk) {
    const int kkg = kh * 18 + kk;
    short8 A = *(const short8*)(aP + (size_t)kkg * 512);
    short8 B = *(const short8*)(bP + (size_t)kkg * 512);
    acc = __builtin_amdgcn_mfma_f32_32x32x16_bf16(A, B, acc, 0, 0, 0);
  }

  __shared__ float red[2][64][17];
  if (kh == 1) {
#pragma unroll
    for (int r = 0; r < 16; ++r) red[octile][lane][r] = acc[r];
  }
  __syncthreads();
  if (kh == 0) {
#pragma unroll
    for (int r = 0; r < 16; ++r) {
      const int oc = octile * 32 + (r & 3) + 8 * (r >> 2) + 4 * half;
      float v = acc[r] + red[octile][lane][r] + bias[oc];
      if (LRELU) v = (v >= 0.f) ? v : 0.1f * v;
      out[((size_t)b * NFEAT + oc) * HWP + pix] = v;
    }
  }
}

// ---------------------------------------------------------------------------
extern "C" void kernel_launch(void* const* d_in, const int* in_sizes, int n_in,
                              void* d_out, int out_size, void* d_ws, size_t ws_size,
                              hipStream_t stream) {
  const float* nbr = (const float*)d_in[0];
  const float* ref = (const float*)d_in[1];
  auto f = [&](int i) { return (const float*)d_in[i]; };

  float* ws = (float*)d_ws;
  const size_t FSZ = (size_t)BATCH * NFEAT * HWP;   // 2,359,296 floats
  const size_t OMSZ = (size_t)BATCH * 216 * HWP;    // 7,962,624 floats
  float* bufA = ws;
  float* bufB = ws + FSZ;
  float* bufC = ws + 2 * FSZ;
  float* bufD = ws + 3 * FSZ;
  float* omB = ws + 4 * FSZ;
  float* wts = ws + 4 * FSZ + OMSZ;                      // 737,280 floats
  short* wbf = (short*)(wts + 737280);                   // 589,824 shorts
  short* pixB = (short*)(wts + 737280 + 294912);         // 2,359,296 shorts
  short* wdcn = (short*)(wts + 737280 + 294912 + 1179648);  // 147,456 shorts
  short* Sbuf = (short*)(wts + 737280 + 294912 + 1179648 + 73728);  // 21,233,664 shorts
  short* nbrT16 = (short*)d_out;  // (b,hw,64) bf16, dead before final write

  // ---- weight prep ----
  static const int srcIdx[20] = {2, 4, 6, 8, 10, 12, 14, 18, 20, 16,
                                 22, 24, 26, 30, 32, 28, 34, 36, 38, 40};
  static const int ocnA[20] = {64, 64, 216, 64, 64, 64, 64, 216, 64, 64,
                               64, 64, 64, 216, 64, 64, 64, 64, 216, 64};
  static const int ickA[20] = {144, 72, 576, 576, 144, 144, 72, 576, 576, 144,
                               144, 144, 72, 576, 576, 144, 144, 72, 576, 576};
  PrepArgs pa;
  int base = 0;
  const float* wt[20];
  for (int t = 0; t < 20; ++t) {
    pa.src[t] = f(srcIdx[t]);
    pa.ocn[t] = ocnA[t];
    pa.ick[t] = ickA[t];
    pa.base[t] = base;
    wt[t] = wts + base;
    base += ocnA[t] * ickA[t];
  }
  pa.base[20] = base;  // 737,280
  prep_kernel<<<(base + 255) / 256, 256, 0, stream>>>(pa, wts);
  prep_om<<<(4 * 147456 + 255) / 256, 256, 0, stream>>>(f(6), f(18), f(30), f(38), wbf);
  prep_dcnw<<<(4 * 36864 + 255) / 256, 256, 0, stream>>>(f(8), f(20), f(32), f(40), wdcn);
  short* wbf_l3 = wbf;
  short* wbf_l2 = wbf + 147456;
  short* wbf_l1 = wbf + 2 * 147456;
  short* wbf_cas = wbf + 3 * 147456;
  short* wd_l3 = wdcn;
  short* wd_l2 = wdcn + 36864;
  short* wd_l1 = wdcn + 2 * 36864;
  short* wd_cas = wdcn + 3 * 36864;

  dim3 gcGrid(3, 12, BATCH * 8), gcBlk(32, 8);
  dim3 omGrid(144, BATCH), omBlk(64, 4);
  dim3 smGrid(288, BATCH), smBlk(32, 8);
  dim3 dgGrid(288, BATCH), dgBlk(64, 4);
  dim3 trGrid(HWP / 64, BATCH), trBlk(64, 4);

  transpose_bf16<<<trGrid, trBlk, 0, stream>>>(nbr, nbrT16);

  // ---- level 3 (dilation 5) ----
  gconv_kernel<16, true, true, false><<<gcGrid, gcBlk, 0, stream>>>(nbr, ref, wt[0], f(3), bufA, nullptr);
  gconv_kernel<8, true, false, true><<<gcGrid, gcBlk, 0, stream>>>(bufA, nullptr, wt[1], f(5), bufB, pixB);
  omconv_mfma<5><<<omGrid, omBlk, 0, stream>>>(pixB, wbf_l3, f(7), omB);
  dcn_sample<5><<<smGrid, smBlk, 0, stream>>>(nbrT16, omB, Sbuf);
  dcn_gemm<true><<<dgGrid, dgBlk, 0, stream>>>(Sbuf, wd_l3, f(9), bufC);
  // bufB = to (off_l3), bufC = tf (feat_l3)

  // ---- level 2 (dilation 3) ----
  gconv_kernel<16, true, true, false><<<gcGrid, gcBlk, 0, stream>>>(nbr, ref, wt[4], f(11), bufA, nullptr);
  gconv_kernel<16, true, true, false><<<gcGrid, gcBlk, 0, stream>>>(bufA, bufB, wt[5], f(13), bufD, nullptr);
  gconv_kernel<8, true, false, true><<<gcGrid, gcBlk, 0, stream>>>(bufD, nullptr, wt[6], f(15), bufA, pixB);
  omconv_mfma<3><<<omGrid, omBlk, 0, stream>>>(pixB, wbf_l2, f(19), omB);
  dcn_sample<3><<<smGrid, smBlk, 0, stream>>>(nbrT16, omB, Sbuf);
  dcn_gemm<false><<<dgGrid, dgBlk, 0, stream>>>(Sbuf, wd_l2, f(21), bufB);
  gconv_kernel<16, true, true, false><<<gcGrid, gcBlk, 0, stream>>>(bufB, bufC, wt[9], f(17), bufD, nullptr);
  // bufA = to (off_l2), bufD = tf (feat_l2)

  // ---- level 1 (dilation 1) ----
  gconv_kernel<16, true, true, false><<<gcGrid, gcBlk, 0, stream>>>(nbr, ref, wt[10], f(23), bufB, nullptr);
  gconv_kernel<16, true, true, false><<<gcGrid, gcBlk, 0, stream>>>(bufB, bufA, wt[11], f(25), bufC, nullptr);
  gconv_kernel<8, true, false, true><<<gcGrid, gcBlk, 0, stream>>>(bufC, nullptr, wt[12], f(27), bufB, pixB);
  omconv_mfma<1><<<omGrid, omBlk, 0, stream>>>(pixB, wbf_l1, f(31), omB);
  dcn_sample<1><<<smGrid, smBlk, 0, stream>>>(nbrT16, omB, Sbuf);
  dcn_gemm<false><<<dgGrid, dgBlk, 0, stream>>>(Sbuf, wd_l1, f(33), bufC);
  gconv_kernel<16, false, true, false><<<gcGrid, gcBlk, 0, stream>>>(bufC, bufD, wt[15], f(29), bufA, nullptr);
  // bufA = feat after l1 (no lrelu); nbrT16 (in d_out) now dead

  // ---- cascade (dilation 1) ----
  short* featT16 = (short*)bufD;  // bufD dead after l1 fc conv
  transpose_bf16<<<trGrid, trBlk, 0, stream>>>(bufA, featT16);
  gconv_kernel<16, true, true, false><<<gcGrid, gcBlk, 0, stream>>>(bufA, ref, wt[16], f(35), bufB, nullptr);
  gconv_kernel<8, true, false, true><<<gcGrid, gcBlk, 0, stream>>>(bufB, nullptr, wt[17], f(37), bufC, pixB);
  omconv_mfma<1><<<omGrid, omBlk, 0, stream>>>(pixB, wbf_cas, f(39), omB);
  dcn_sample<1><<<smGrid, smBlk, 0, stream>>>(featT16, omB, Sbuf);
  dcn_gemm<true><<<dgGrid, dgBlk, 0, stream>>>(Sbuf, wd_cas, f(41), (float*)d_out);
}

// Round 8
// 567.949 us; speedup vs baseline: 4.2517x; 1.1400x over previous
//
#include <hip/hip_runtime.h>

#define BATCH 4
#define NFEAT 64
#define DGRP 8
#define HH 96
#define WW 96
#define HWP (HH*WW)

typedef short short4a __attribute__((ext_vector_type(4)));
typedef short short8 __attribute__((ext_vector_type(8)));
typedef float f32x4 __attribute__((ext_vector_type(4)));
typedef float f32x16 __attribute__((ext_vector_type(16)));

__device__ inline short f2bf(float f) {
  union { float f; unsigned u; } v; v.f = f;
  unsigned r = v.u + 0x7fff + ((v.u >> 16) & 1);
  return (short)(r >> 16);
}
__device__ inline float bf2f(short s) {
  return __uint_as_float(((unsigned)(unsigned short)s) << 16);
}

// ---------------------------------------------------------------------------
// om-weight prep, 32x32 MFMA-A-fragment-shuffled (proven R6):
// dst[t][tile(8)][kk(36)][lane(64)][8]; k = kk*16 + half*8 + j = p*64+c.
// ---------------------------------------------------------------------------
__global__ __launch_bounds__(256) void prep_om(
    const float* __restrict__ s0, const float* __restrict__ s1,
    const float* __restrict__ s2, const float* __restrict__ s3,
    short* __restrict__ dst) {
  int gid = blockIdx.x * 256 + threadIdx.x;
  if (gid >= 4 * 147456) return;
  int t = gid / 147456, r = gid % 147456;
  int tile = r / 18432, r2 = r % 18432;
  int kk = r2 / 512, r3 = r2 % 512;
  int lane = r3 / 8, j = r3 % 8;
  int col = lane & 31, half = lane >> 5;
  int oc = tile * 32 + col;
  int k = kk * 16 + half * 8 + j;
  int p = k >> 6, c = k & 63;
  const float* s = (t == 0) ? s0 : (t == 1) ? s1 : (t == 2) ? s2 : s3;
  float v = (oc < 216) ? s[(size_t)oc * 576 + c * 9 + p] : 0.f;
  dst[gid] = f2bf(v);
}

// ---------------------------------------------------------------------------
// dcn-weight prep, same 32x32 A-shuffle: dst[t][tile(2)][kk(36)][lane][8].
// ---------------------------------------------------------------------------
__global__ __launch_bounds__(256) void prep_dcnw(
    const float* __restrict__ s0, const float* __restrict__ s1,
    const float* __restrict__ s2, const float* __restrict__ s3,
    short* __restrict__ dst) {
  int gid = blockIdx.x * 256 + threadIdx.x;
  if (gid >= 4 * 36864) return;
  int t = gid / 36864, r = gid % 36864;
  int tile = r / 18432, r2 = r % 18432;
  int kk = r2 / 512, r3 = r2 % 512;
  int lane = r3 / 8, j = r3 % 8;
  int col = lane & 31, half = lane >> 5;
  int oc = tile * 32 + col;
  int k = kk * 16 + half * 8 + j;
  int p = k >> 6, c = k & 63;
  const float* s = (t == 0) ? s0 : (t == 1) ? s1 : (t == 2) ? s2 : s3;
  dst[gid] = f2bf(s[(size_t)oc * 576 + c * 9 + p]);
}

// ---------------------------------------------------------------------------
// gconv weight prep: 16x16x32 A fragments, group-pair block-diagonal,
// cat_align folded in. dst[t][tile(4)][kk(9|5)][lane(64)][8].
// CAT: K-chunk(32) per tap = [g_lo: in0 8ch, in1 8ch | g_hi: ...]; value 0
// when the k-slot's group != oc's group. NOCAT: chunk = 2 taps x 16ch.
// ---------------------------------------------------------------------------
struct GwArgs {
  const float* src[12];
  int cat[12];
  int base[13];
};

__global__ __launch_bounds__(256) void prep_gw(GwArgs a, short* __restrict__ dst) {
  int gid = blockIdx.x * 256 + threadIdx.x;
  if (gid >= a.base[12]) return;
  int t = 0;
  while (gid >= a.base[t + 1]) ++t;
  int r = gid - a.base[t];
  const float* s = a.src[t];
  const int tsz = a.cat[t] ? 4608 : 2560;
  int tile = r / tsz, r2 = r % tsz;
  int kk = r2 / 512, r3 = r2 % 512;
  int lane = r3 >> 3, j = r3 & 7;
  int m = lane & 15, quad = lane >> 4;
  int oc = tile * 16 + m;
  int j32 = quad * 8 + j;
  float val = 0.f;
  if (a.cat[t]) {
    int gsel = j32 >> 4, ssel = (j32 >> 3) & 1, ch8 = j32 & 7;
    if (gsel == (m >> 3)) val = s[oc * 144 + (2 * ch8 + ssel) * 9 + kk];
  } else {
    int tapsel = j32 >> 4, gsel = (j32 >> 3) & 1, ch8 = j32 & 7;
    int p = 2 * kk + tapsel;
    if (p < 9 && gsel == (m >> 3)) val = s[oc * 72 + ch8 * 9 + p];
  }
  dst[gid] = f2bf(val);
}

// ---------------------------------------------------------------------------
// Channel-major (b,64,hw) fp32 -> pixel-major (b,hw,64) bf16.
// ---------------------------------------------------------------------------
__global__ __launch_bounds__(256) void transpose_bf16(
    const float* __restrict__ in, short* __restrict__ out) {
  __shared__ float s[64][65];
  const int p0 = blockIdx.x * 64;
  const int b = blockIdx.y;
  const int tx = threadIdx.x, ty = threadIdx.y;
  for (int c = ty; c < 64; c += 4)
    s[c][tx] = in[((size_t)b * NFEAT + c) * HWP + p0 + tx];
  __syncthreads();
  for (int p = ty; p < 64; p += 4)
    out[((size_t)b * HWP + p0 + p) * NFEAT + tx] = f2bf(s[tx][p]);
}

// ---------------------------------------------------------------------------
// Grouped 3x3 conv (dil=1, pad=1, groups=8) on 16x16x32 MFMA.
// Block (64,4): wave t = group-pair tile (16 oc), 32 pixels (2 N-tiles).
// Grid (288, BATCH). In/out: bf16 pixel-major (b,hw,64).
// A: prep-shuffled coalesced 1KB loads. B: one short8 per lane per K-chunk.
// ---------------------------------------------------------------------------
template <bool CAT, bool LRELU>
__global__ __launch_bounds__(256) void gconv_mfma(
    const short* __restrict__ in0, const short* __restrict__ in1,
    const short* __restrict__ Wsh, const float* __restrict__ bias,
    short* __restrict__ out) {
  const int lane = threadIdx.x, t = threadIdx.y;
  const int n = lane & 15, quad = lane >> 4;
  const int pixbase = blockIdx.x * 32;
  const int b = blockIdx.y;
  constexpr int NKK = CAT ? 9 : 5;

  short8 A[NKK];
#pragma unroll
  for (int kk = 0; kk < NKK; ++kk)
    A[kk] = *(const short8*)(Wsh + ((size_t)(t * NKK + kk) * 64 + lane) * 8);

  const short* sb;
  if (CAT) {
    sb = ((quad & 1) ? in1 : in0) + (size_t)b * HWP * 64 + (2 * t + (quad >> 1)) * 8;
  } else {
    sb = in0 + (size_t)b * HWP * 64 + (2 * t + (quad & 1)) * 8;
  }

  f32x4 acc[2] = {};
#pragma unroll
  for (int nt = 0; nt < 2; ++nt) {
    const int pix = pixbase + nt * 16 + n;
    const int yp = pix / WW, xp = pix % WW;
#pragma unroll
    for (int kk = 0; kk < NKK; ++kk) {
      const int p = CAT ? kk : (2 * kk + (quad >> 1));
      short8 B = {0, 0, 0, 0, 0, 0, 0, 0};
      if (p < 9) {
        const int sy = yp + p / 3 - 1, sx = xp + p % 3 - 1;
        if (((unsigned)sy < (unsigned)HH) && ((unsigned)sx < (unsigned)WW))
          B = *(const short8*)(sb + (size_t)(sy * WW + sx) * 64);
      }
      acc[nt] = __builtin_amdgcn_mfma_f32_16x16x32_bf16(A[kk], B, acc[nt], 0, 0, 0);
    }
  }

  const int ocb = t * 16 + quad * 4;
  const float b0 = bias[ocb], b1 = bias[ocb + 1], b2 = bias[ocb + 2], b3 = bias[ocb + 3];
#pragma unroll
  for (int nt = 0; nt < 2; ++nt) {
    float v0 = acc[nt][0] + b0, v1 = acc[nt][1] + b1;
    float v2 = acc[nt][2] + b2, v3 = acc[nt][3] + b3;
    if (LRELU) {
      v0 = (v0 >= 0.f) ? v0 : 0.1f * v0;
      v1 = (v1 >= 0.f) ? v1 : 0.1f * v1;
      v2 = (v2 >= 0.f) ? v2 : 0.1f * v2;
      v3 = (v3 >= 0.f) ? v3 : 0.1f * v3;
    }
    short4a pk = {f2bf(v0), f2bf(v1), f2bf(v2), f2bf(v3)};
    *(short4a*)(out + ((size_t)b * HWP + pixbase + nt * 16 + n) * 64 + ocb) = pk;
  }
}

// ---------------------------------------------------------------------------
// Offset/mask conv v3 (proven R6): LDS-staged B, shuffled A, 2x2 blocking.
// ---------------------------------------------------------------------------
#define BPITCH 324
template <int D>
__global__ __launch_bounds__(256) void omconv_mfma(
    const short* __restrict__ pixT,  // (b, hw, 64) bf16
    const short* __restrict__ Wsh,   // shuffled [tile(8)][kk(36)][lane][8]
    const float* __restrict__ bias,  // (216)
    float* __restrict__ out) {       // (b, 216, hw) fp32
  const int lane = threadIdx.x;
  const int w = threadIdx.y;
  const int lid = w * 64 + lane;
  const int col = lane & 31, half = lane >> 5;
  const int pixbase = blockIdx.x * 64;
  const int b = blockIdx.y;

  __shared__ short Bs[64 * BPITCH];

  const short* aP0 = Wsh + ((size_t)(w * 36) * 64) * 8 + (size_t)lane * 8;
  const short* aP1 = Wsh + ((size_t)((w + 4) * 36) * 64) * 8 + (size_t)lane * 8;
  const short* pixb = pixT + (size_t)b * HWP * 64;

  f32x16 acc00 = {}, acc01 = {}, acc10 = {}, acc11 = {};

  for (int ph = 0; ph < 2; ++ph) {
    const int ntap = ph ? 4 : 5, pbase = ph ? 5 : 0, kbase = ph ? 20 : 0;
    if (ph) __syncthreads();
    const int nchunk = 64 * ntap * 8;
    for (int i = lid; i < nchunk; i += 256) {
      int row = i / (ntap * 8), q = i % (ntap * 8);
      int p = pbase + (q >> 3), c8 = q & 7;
      int pix = pixbase + row;
      int yp = pix / WW, xp = pix % WW;
      int sy = yp + (p / 3 - 1) * D, sx = xp + (p % 3 - 1) * D;
      short4a lo = {0, 0, 0, 0}, hi = {0, 0, 0, 0};
      if (((unsigned)sy < (unsigned)HH) && ((unsigned)sx < (unsigned)WW)) {
        const short* src = pixb + (size_t)(sy * WW + sx) * 64 + c8 * 8;
        lo = *(const short4a*)src;
        hi = *(const short4a*)(src + 4);
      }
      short* dst = Bs + row * BPITCH + q * 8;
      *(short4a*)dst = lo;
      *(short4a*)(dst + 4) = hi;
    }
    __syncthreads();

    const int nkk = ntap * 4;
#pragma unroll 4
    for (int kk = 0; kk < nkk; ++kk) {
      const int kkg = kbase + kk;
      short8 A0 = *(const short8*)(aP0 + (size_t)kkg * 512);
      short8 A1 = *(const short8*)(aP1 + (size_t)kkg * 512);
      const short* b0 = Bs + col * BPITCH + kk * 16 + half * 8;
      const short* b1 = Bs + (32 + col) * BPITCH + kk * 16 + half * 8;
      short4a l0 = *(const short4a*)b0, h0 = *(const short4a*)(b0 + 4);
      short4a l1 = *(const short4a*)b1, h1 = *(const short4a*)(b1 + 4);
      short8 B0 = {l0[0], l0[1], l0[2], l0[3], h0[0], h0[1], h0[2], h0[3]};
      short8 B1 = {l1[0], l1[1], l1[2], l1[3], h1[0], h1[1], h1[2], h1[3]};
      acc00 = __builtin_amdgcn_mfma_f32_32x32x16_bf16(A0, B0, acc00, 0, 0, 0);
      acc01 = __builtin_amdgcn_mfma_f32_32x32x16_bf16(A0, B1, acc01, 0, 0, 0);
      acc10 = __builtin_amdgcn_mfma_f32_32x32x16_bf16(A1, B0, acc10, 0, 0, 0);
      acc11 = __builtin_amdgcn_mfma_f32_32x32x16_bf16(A1, B1, acc11, 0, 0, 0);
    }
  }

  const int pix0 = pixbase + col, pix1 = pixbase + 32 + col;
#pragma unroll
  for (int r = 0; r < 16; ++r) {
    const int rrow = (r & 3) + 8 * (r >> 2) + 4 * half;
    const int oc0 = w * 32 + rrow;
    const int oc1 = (w + 4) * 32 + rrow;
    const float bs0 = bias[oc0];
    out[((size_t)b * 216 + oc0) * HWP + pix0] = acc00[r] + bs0;
    out[((size_t)b * 216 + oc0) * HWP + pix1] = acc01[r] + bs0;
    if (oc1 < 216) {
      const float bs1 = bias[oc1];
      out[((size_t)b * 216 + oc1) * HWP + pix0] = acc10[r] + bs1;
      out[((size_t)b * 216 + oc1) * HWP + pix1] = acc11[r] + bs1;
    }
  }
}

// ---------------------------------------------------------------------------
// DCN stage 1 (proven R6): bilinear sampling -> S in B-fragment order.
// ---------------------------------------------------------------------------
template <int D>
__global__ __launch_bounds__(256) void dcn_sample(
    const short* __restrict__ xT,   // (b, hw, 64) bf16 pixel-major
    const float* __restrict__ om,   // (b, 216, hw) fp32 raw
    short* __restrict__ S) {
  const int px = threadIdx.x;
  const int dg = threadIdx.y;
  const int pb = blockIdx.x;
  const int b = blockIdx.y;
  const int pix = pb * 32 + px;
  const int yp = pix / WW, xp = pix % WW;
  const size_t bOM = (size_t)b * 216 * HWP;
  const short* xb = xT + (size_t)b * HWP * 64 + dg * 8;
  const int lane = (dg & 1) * 32 + px;
  short* Sp = S + (((size_t)(b * 288 + pb) * 36) * 64 + lane) * 8;

#pragma unroll
  for (int k = 0; k < 9; ++k) {
    float dy = om[bOM + (size_t)(dg * 18 + 2 * k) * HWP + pix];
    float dxv = om[bOM + (size_t)(dg * 18 + 2 * k + 1) * HWP + pix];
    float mr = om[bOM + (size_t)(144 + dg * 9 + k) * HWP + pix];
    float m = 1.f / (1.f + __expf(-mr));
    float py = (float)(yp + (k / 3 - 1) * D) + dy;
    float px_ = (float)(xp + (k % 3 - 1) * D) + dxv;
    float y0f = floorf(py), x0f = floorf(px_);
    float ly = py - y0f, lx = px_ - x0f;
    int y0 = (int)y0f, x0 = (int)x0f;
    int y1 = y0 + 1, x1 = x0 + 1;
    bool vy0 = (unsigned)y0 < (unsigned)HH, vy1 = (unsigned)y1 < (unsigned)HH;
    bool vx0 = (unsigned)x0 < (unsigned)WW, vx1 = (unsigned)x1 < (unsigned)WW;
    int cy0 = min(max(y0, 0), HH - 1), cy1 = min(max(y1, 0), HH - 1);
    int cx0 = min(max(x0, 0), WW - 1), cx1 = min(max(x1, 0), WW - 1);
    float w00 = (vy0 && vx0) ? (1.f - ly) * (1.f - lx) * m : 0.f;
    float w01 = (vy0 && vx1) ? (1.f - ly) * lx * m : 0.f;
    float w10 = (vy1 && vx0) ? ly * (1.f - lx) * m : 0.f;
    float w11 = (vy1 && vx1) ? ly * lx * m : 0.f;
    short8 s00 = *(const short8*)(xb + (size_t)(cy0 * WW + cx0) * 64);
    short8 s01 = *(const short8*)(xb + (size_t)(cy0 * WW + cx1) * 64);
    short8 s10 = *(const short8*)(xb + (size_t)(cy1 * WW + cx0) * 64);
    short8 s11 = *(const short8*)(xb + (size_t)(cy1 * WW + cx1) * 64);
    short8 pk;
#pragma unroll
    for (int cl = 0; cl < 8; ++cl) {
      float v = w00 * bf2f(s00[cl]) + w01 * bf2f(s01[cl]) +
                w10 * bf2f(s10[cl]) + w11 * bf2f(s11[cl]);
      pk[cl] = f2bf(v);
    }
    const int kk = k * 4 + (dg >> 1);
    *(short8*)(Sp + (size_t)kk * 512) = pk;
  }
}

// ---------------------------------------------------------------------------
// DCN stage 2 (proven R6) + PMOUT epilogue option (bf16 pixel-major).
// ---------------------------------------------------------------------------
template <bool LRELU, bool PMOUT>
__global__ __launch_bounds__(256) void dcn_gemm(
    const short* __restrict__ S,
    const short* __restrict__ Wd,
    const float* __restrict__ bias,
    void* __restrict__ outv) {
  const int lane = threadIdx.x;
  const int w = threadIdx.y;
  const int col = lane & 31, half = lane >> 5;
  const int octile = w & 1, kh = w >> 1;
  const int pb = blockIdx.x;
  const int b = blockIdx.y;
  const int pix = pb * 32 + col;

  const short* aP = Wd + ((size_t)(octile * 36) * 64 + lane) * 8;
  const short* bP = S + (((size_t)(b * 288 + pb) * 36) * 64 + lane) * 8;

  f32x16 acc = {};
#pragma unroll 6
  for (int kk = 0; kk < 18; ++kk) {
    const int kkg = kh * 18 + kk;
    short8 A = *(const short8*)(aP + (size_t)kkg * 512);
    short8 B = *(const short8*)(bP + (size_t)kkg * 512);
    acc = __builtin_amdgcn_mfma_f32_32x32x16_bf16(A, B, acc, 0, 0, 0);
  }

  __shared__ float red[2][64][17];
  if (kh == 1) {
#pragma unroll
    for (int r = 0; r < 16; ++r) red[octile][lane][r] = acc[r];
  }
  __syncthreads();
  if (kh == 0) {
    if (PMOUT) {
      short* out = (short*)outv;
#pragma unroll
      for (int rg = 0; rg < 4; ++rg) {
        short4a pk;
#pragma unroll
        for (int i = 0; i < 4; ++i) {
          const int r = rg * 4 + i;
          const int oc = octile * 32 + i + 8 * rg + 4 * half;
          float v = acc[r] + red[octile][lane][r] + bias[oc];
          if (LRELU) v = (v >= 0.f) ? v : 0.1f * v;
          pk[i] = f2bf(v);
        }
        *(short4a*)(out + ((size_t)b * HWP + pix) * 64 + octile * 32 + 8 * rg + 4 * half) = pk;
      }
    } else {
      float* out = (float*)outv;
#pragma unroll
      for (int r = 0; r < 16; ++r) {
        const int oc = octile * 32 + (r & 3) + 8 * (r >> 2) + 4 * half;
        float v = acc[r] + red[octile][lane][r] + bias[oc];
        if (LRELU) v = (v >= 0.f) ? v : 0.1f * v;
        out[((size_t)b * NFEAT + oc) * HWP + pix] = v;
      }
    }
  }
}

// ---------------------------------------------------------------------------
extern "C" void kernel_launch(void* const* d_in, const int* in_sizes, int n_in,
                              void* d_out, int out_size, void* d_ws, size_t ws_size,
                              hipStream_t stream) {
  const float* nbr = (const float*)d_in[0];
  const float* ref = (const float*)d_in[1];
  auto f = [&](int i) { return (const float*)d_in[i]; };

  float* ws = (float*)d_ws;
  const size_t PM = (size_t)BATCH * HWP * 64;        // 2,359,296 shorts per PM buffer
  float* omB = ws;                                   // 7,962,624 floats
  short* sb = (short*)(ws + 7962624);
  short* refT = sb;
  short* pmA = refT + PM;
  short* pmB = pmA + PM;
  short* pmC = pmB + PM;
  short* pmD = pmC + PM;
  short* pmE = pmD + PM;
  short* Sbuf = pmE + PM;                            // 21,233,664 shorts
  short* wbf = Sbuf + 21233664;                      // 589,824
  short* wdcn = wbf + 589824;                        // 147,456
  short* wgc = wdcn + 147456;                        // 188,416
  short* nbrT = (short*)d_out;                       // dead before final write

  // ---- weight prep ----
  prep_om<<<(4 * 147456 + 255) / 256, 256, 0, stream>>>(f(6), f(18), f(30), f(38), wbf);
  prep_dcnw<<<(4 * 36864 + 255) / 256, 256, 0, stream>>>(f(8), f(20), f(32), f(40), wdcn);

  // gconv weights: order l3{oc1,oc2} l2{oc1,oc2,oc3,fc} l1{oc1,oc2,oc3,fc} cas{oc1,oc2}
  static const int gSrc[12] = {2, 4, 10, 12, 14, 16, 22, 24, 26, 28, 34, 36};
  static const int gCat[12] = {1, 0, 1, 1, 0, 1, 1, 1, 0, 1, 1, 0};
  GwArgs ga;
  int gb = 0;
  const short* wg[12];
  for (int t = 0; t < 12; ++t) {
    ga.src[t] = f(gSrc[t]);
    ga.cat[t] = gCat[t];
    ga.base[t] = gb;
    wg[t] = wgc + gb;
    gb += gCat[t] ? 18432 : 10240;
  }
  ga.base[12] = gb;  // 188,416
  prep_gw<<<(gb + 255) / 256, 256, 0, stream>>>(ga, wgc);

  short* wbf_l3 = wbf;
  short* wbf_l2 = wbf + 147456;
  short* wbf_l1 = wbf + 2 * 147456;
  short* wbf_cas = wbf + 3 * 147456;
  short* wd_l3 = wdcn;
  short* wd_l2 = wdcn + 36864;
  short* wd_l1 = wdcn + 2 * 36864;
  short* wd_cas = wdcn + 3 * 36864;

  dim3 gcGrid(288, BATCH), gcBlk(64, 4);
  dim3 omGrid(144, BATCH), omBlk(64, 4);
  dim3 smGrid(288, BATCH), smBlk(32, 8);
  dim3 dgGrid(288, BATCH), dgBlk(64, 4);
  dim3 trGrid(HWP / 64, BATCH), trBlk(64, 4);

  transpose_bf16<<<trGrid, trBlk, 0, stream>>>(nbr, nbrT);
  transpose_bf16<<<trGrid, trBlk, 0, stream>>>(ref, refT);

  // ---- level 3 (dilation 5) ----
  gconv_mfma<true, true><<<gcGrid, gcBlk, 0, stream>>>(nbrT, refT, wg[0], f(3), pmA);
  gconv_mfma<false, true><<<gcGrid, gcBlk, 0, stream>>>(pmA, nullptr, wg[1], f(5), pmB);
  omconv_mfma<5><<<omGrid, omBlk, 0, stream>>>(pmB, wbf_l3, f(7), omB);
  dcn_sample<5><<<smGrid, smBlk, 0, stream>>>(nbrT, omB, Sbuf);
  dcn_gemm<true, true><<<dgGrid, dgBlk, 0, stream>>>(Sbuf, wd_l3, f(9), pmC);
  // pmB = to_l3, pmC = tf_l3

  // ---- level 2 (dilation 3) ----
  gconv_mfma<true, true><<<gcGrid, gcBlk, 0, stream>>>(nbrT, refT, wg[2], f(11), pmA);
  gconv_mfma<true, true><<<gcGrid, gcBlk, 0, stream>>>(pmA, pmB, wg[3], f(13), pmD);
  gconv_mfma<false, true><<<gcGrid, gcBlk, 0, stream>>>(pmD, nullptr, wg[4], f(15), pmE);
  omconv_mfma<3><<<omGrid, omBlk, 0, stream>>>(pmE, wbf_l2, f(19), omB);
  dcn_sample<3><<<smGrid, smBlk, 0, stream>>>(nbrT, omB, Sbuf);
  dcn_gemm<false, true><<<dgGrid, dgBlk, 0, stream>>>(Sbuf, wd_l2, f(21), pmD);
  gconv_mfma<true, true><<<gcGrid, gcBlk, 0, stream>>>(pmD, pmC, wg[5], f(17), pmA);
  // pmE = to_l2, pmA = tf_l2

  // ---- level 1 (dilation 1) ----
  gconv_mfma<true, true><<<gcGrid, gcBlk, 0, stream>>>(nbrT, refT, wg[6], f(23), pmC);
  gconv_mfma<true, true><<<gcGrid, gcBlk, 0, stream>>>(pmC, pmE, wg[7], f(25), pmD);
  gconv_mfma<false, true><<<gcGrid, gcBlk, 0, stream>>>(pmD, nullptr, wg[8], f(27), pmC);
  omconv_mfma<1><<<omGrid, omBlk, 0, stream>>>(pmC, wbf_l1, f(31), omB);
  dcn_sample<1><<<smGrid, smBlk, 0, stream>>>(nbrT, omB, Sbuf);
  dcn_gemm<false, true><<<dgGrid, dgBlk, 0, stream>>>(Sbuf, wd_l1, f(33), pmD);
  gconv_mfma<true, false><<<gcGrid, gcBlk, 0, stream>>>(pmD, pmA, wg[9], f(29), pmB);
  // pmB = feat (no lrelu); nbrT (in d_out) now dead

  // ---- cascade (dilation 1) ----
  gconv_mfma<true, true><<<gcGrid, gcBlk, 0, stream>>>(pmB, refT, wg[10], f(35), pmC);
  gconv_mfma<false, true><<<gcGrid, gcBlk, 0, stream>>>(pmC, nullptr, wg[11], f(37), pmD);
  omconv_mfma<1><<<omGrid, omBlk, 0, stream>>>(pmD, wbf_cas, f(39), omB);
  dcn_sample<1><<<smGrid, smBlk, 0, stream>>>(pmB, omB, Sbuf);
  dcn_gemm<true, false><<<dgGrid, dgBlk, 0, stream>>>(Sbuf, wd_cas, f(41), (float*)d_out);
}

// Round 9
// 528.060 us; speedup vs baseline: 4.5728x; 1.0755x over previous
//
#include <hip/hip_runtime.h>

#define BATCH 4
#define NFEAT 64
#define DGRP 8
#define HH 96
#define WW 96
#define HWP (HH*WW)

typedef short short4a __attribute__((ext_vector_type(4)));
typedef short short8 __attribute__((ext_vector_type(8)));
typedef float f32x4 __attribute__((ext_vector_type(4)));
typedef float f32x16 __attribute__((ext_vector_type(16)));

__device__ inline short f2bf(float f) {
  union { float f; unsigned u; } v; v.f = f;
  unsigned r = v.u + 0x7fff + ((v.u >> 16) & 1);
  return (short)(r >> 16);
}
__device__ inline float bf2f(short s) {
  return __uint_as_float(((unsigned)(unsigned short)s) << 16);
}

// ---------------------------------------------------------------------------
// om-weight prep, 32x32 MFMA-A-fragment-shuffled (proven R6):
// dst[t][tile(8)][kk(36)][lane(64)][8]; k = kk*16 + half*8 + j = p*64+c.
// ---------------------------------------------------------------------------
__global__ __launch_bounds__(256) void prep_om(
    const float* __restrict__ s0, const float* __restrict__ s1,
    const float* __restrict__ s2, const float* __restrict__ s3,
    short* __restrict__ dst) {
  int gid = blockIdx.x * 256 + threadIdx.x;
  if (gid >= 4 * 147456) return;
  int t = gid / 147456, r = gid % 147456;
  int tile = r / 18432, r2 = r % 18432;
  int kk = r2 / 512, r3 = r2 % 512;
  int lane = r3 / 8, j = r3 % 8;
  int col = lane & 31, half = lane >> 5;
  int oc = tile * 32 + col;
  int k = kk * 16 + half * 8 + j;
  int p = k >> 6, c = k & 63;
  const float* s = (t == 0) ? s0 : (t == 1) ? s1 : (t == 2) ? s2 : s3;
  float v = (oc < 216) ? s[(size_t)oc * 576 + c * 9 + p] : 0.f;
  dst[gid] = f2bf(v);
}

// ---------------------------------------------------------------------------
// dcn-weight prep, same 32x32 A-shuffle: dst[t][tile(2)][kk(36)][lane][8].
// ---------------------------------------------------------------------------
__global__ __launch_bounds__(256) void prep_dcnw(
    const float* __restrict__ s0, const float* __restrict__ s1,
    const float* __restrict__ s2, const float* __restrict__ s3,
    short* __restrict__ dst) {
  int gid = blockIdx.x * 256 + threadIdx.x;
  if (gid >= 4 * 36864) return;
  int t = gid / 36864, r = gid % 36864;
  int tile = r / 18432, r2 = r % 18432;
  int kk = r2 / 512, r3 = r2 % 512;
  int lane = r3 / 8, j = r3 % 8;
  int col = lane & 31, half = lane >> 5;
  int oc = tile * 32 + col;
  int k = kk * 16 + half * 8 + j;
  int p = k >> 6, c = k & 63;
  const float* s = (t == 0) ? s0 : (t == 1) ? s1 : (t == 2) ? s2 : s3;
  dst[gid] = f2bf(s[(size_t)oc * 576 + c * 9 + p]);
}

// ---------------------------------------------------------------------------
// gconv weight prep (proven R7): 16x16x32 A frags, group-pair block-diagonal.
// ---------------------------------------------------------------------------
struct GwArgs {
  const float* src[12];
  int cat[12];
  int base[13];
};

__global__ __launch_bounds__(256) void prep_gw(GwArgs a, short* __restrict__ dst) {
  int gid = blockIdx.x * 256 + threadIdx.x;
  if (gid >= a.base[12]) return;
  int t = 0;
  while (gid >= a.base[t + 1]) ++t;
  int r = gid - a.base[t];
  const float* s = a.src[t];
  const int tsz = a.cat[t] ? 4608 : 2560;
  int tile = r / tsz, r2 = r % tsz;
  int kk = r2 / 512, r3 = r2 % 512;
  int lane = r3 >> 3, j = r3 & 7;
  int m = lane & 15, quad = lane >> 4;
  int oc = tile * 16 + m;
  int j32 = quad * 8 + j;
  float val = 0.f;
  if (a.cat[t]) {
    int gsel = j32 >> 4, ssel = (j32 >> 3) & 1, ch8 = j32 & 7;
    if (gsel == (m >> 3)) val = s[oc * 144 + (2 * ch8 + ssel) * 9 + kk];
  } else {
    int tapsel = j32 >> 4, gsel = (j32 >> 3) & 1, ch8 = j32 & 7;
    int p = 2 * kk + tapsel;
    if (p < 9 && gsel == (m >> 3)) val = s[oc * 72 + ch8 * 9 + p];
  }
  dst[gid] = f2bf(val);
}

// ---------------------------------------------------------------------------
// Channel-major fp32 -> pixel-major bf16; z picks (nbr->nbrT, ref->refT).
// ---------------------------------------------------------------------------
__global__ __launch_bounds__(256) void transpose_bf16(
    const float* __restrict__ in0, short* __restrict__ out0,
    const float* __restrict__ in1, short* __restrict__ out1) {
  const float* in = blockIdx.z ? in1 : in0;
  short* out = blockIdx.z ? out1 : out0;
  __shared__ float s[64][65];
  const int p0 = blockIdx.x * 64;
  const int b = blockIdx.y;
  const int tx = threadIdx.x, ty = threadIdx.y;
  for (int c = ty; c < 64; c += 4)
    s[c][tx] = in[((size_t)b * NFEAT + c) * HWP + p0 + tx];
  __syncthreads();
  for (int p = ty; p < 64; p += 4)
    out[((size_t)b * HWP + p0 + p) * NFEAT + tx] = f2bf(s[tx][p]);
}

// ---------------------------------------------------------------------------
// Grouped 3x3 conv on 16x16x32 MFMA (proven R7).
// ---------------------------------------------------------------------------
template <bool CAT, bool LRELU>
__global__ __launch_bounds__(256) void gconv_mfma(
    const short* __restrict__ in0, const short* __restrict__ in1,
    const short* __restrict__ Wsh, const float* __restrict__ bias,
    short* __restrict__ out) {
  const int lane = threadIdx.x, t = threadIdx.y;
  const int n = lane & 15, quad = lane >> 4;
  const int pixbase = blockIdx.x * 32;
  const int b = blockIdx.y;
  constexpr int NKK = CAT ? 9 : 5;

  short8 A[NKK];
#pragma unroll
  for (int kk = 0; kk < NKK; ++kk)
    A[kk] = *(const short8*)(Wsh + ((size_t)(t * NKK + kk) * 64 + lane) * 8);

  const short* sb;
  if (CAT) {
    sb = ((quad & 1) ? in1 : in0) + (size_t)b * HWP * 64 + (2 * t + (quad >> 1)) * 8;
  } else {
    sb = in0 + (size_t)b * HWP * 64 + (2 * t + (quad & 1)) * 8;
  }

  f32x4 acc[2] = {};
#pragma unroll
  for (int nt = 0; nt < 2; ++nt) {
    const int pix = pixbase + nt * 16 + n;
    const int yp = pix / WW, xp = pix % WW;
#pragma unroll
    for (int kk = 0; kk < NKK; ++kk) {
      const int p = CAT ? kk : (2 * kk + (quad >> 1));
      short8 B = {0, 0, 0, 0, 0, 0, 0, 0};
      if (p < 9) {
        const int sy = yp + p / 3 - 1, sx = xp + p % 3 - 1;
        if (((unsigned)sy < (unsigned)HH) && ((unsigned)sx < (unsigned)WW))
          B = *(const short8*)(sb + (size_t)(sy * WW + sx) * 64);
      }
      acc[nt] = __builtin_amdgcn_mfma_f32_16x16x32_bf16(A[kk], B, acc[nt], 0, 0, 0);
    }
  }

  const int ocb = t * 16 + quad * 4;
  const float b0 = bias[ocb], b1 = bias[ocb + 1], b2 = bias[ocb + 2], b3 = bias[ocb + 3];
#pragma unroll
  for (int nt = 0; nt < 2; ++nt) {
    float v0 = acc[nt][0] + b0, v1 = acc[nt][1] + b1;
    float v2 = acc[nt][2] + b2, v3 = acc[nt][3] + b3;
    if (LRELU) {
      v0 = (v0 >= 0.f) ? v0 : 0.1f * v0;
      v1 = (v1 >= 0.f) ? v1 : 0.1f * v1;
      v2 = (v2 >= 0.f) ? v2 : 0.1f * v2;
      v3 = (v3 >= 0.f) ? v3 : 0.1f * v3;
    }
    short4a pk = {f2bf(v0), f2bf(v1), f2bf(v2), f2bf(v3)};
    *(short4a*)(out + ((size_t)b * HWP + pixbase + nt * 16 + n) * 64 + ocb) = pk;
  }
}

// ---------------------------------------------------------------------------
// Offset/mask conv v3 (proven R6), now with bf16 output.
// ---------------------------------------------------------------------------
#define BPITCH 324
template <int D>
__global__ __launch_bounds__(256) void omconv_mfma(
    const short* __restrict__ pixT,  // (b, hw, 64) bf16
    const short* __restrict__ Wsh,   // shuffled [tile(8)][kk(36)][lane][8]
    const float* __restrict__ bias,  // (216)
    short* __restrict__ out) {       // (b, 216, hw) bf16
  const int lane = threadIdx.x;
  const int w = threadIdx.y;
  const int lid = w * 64 + lane;
  const int col = lane & 31, half = lane >> 5;
  const int pixbase = blockIdx.x * 64;
  const int b = blockIdx.y;

  __shared__ short Bs[64 * BPITCH];

  const short* aP0 = Wsh + ((size_t)(w * 36) * 64) * 8 + (size_t)lane * 8;
  const short* aP1 = Wsh + ((size_t)((w + 4) * 36) * 64) * 8 + (size_t)lane * 8;
  const short* pixb = pixT + (size_t)b * HWP * 64;

  f32x16 acc00 = {}, acc01 = {}, acc10 = {}, acc11 = {};

  for (int ph = 0; ph < 2; ++ph) {
    const int ntap = ph ? 4 : 5, pbase = ph ? 5 : 0, kbase = ph ? 20 : 0;
    if (ph) __syncthreads();
    const int nchunk = 64 * ntap * 8;
    for (int i = lid; i < nchunk; i += 256) {
      int row = i / (ntap * 8), q = i % (ntap * 8);
      int p = pbase + (q >> 3), c8 = q & 7;
      int pix = pixbase + row;
      int yp = pix / WW, xp = pix % WW;
      int sy = yp + (p / 3 - 1) * D, sx = xp + (p % 3 - 1) * D;
      short4a lo = {0, 0, 0, 0}, hi = {0, 0, 0, 0};
      if (((unsigned)sy < (unsigned)HH) && ((unsigned)sx < (unsigned)WW)) {
        const short* src = pixb + (size_t)(sy * WW + sx) * 64 + c8 * 8;
        lo = *(const short4a*)src;
        hi = *(const short4a*)(src + 4);
      }
      short* dst = Bs + row * BPITCH + q * 8;
      *(short4a*)dst = lo;
      *(short4a*)(dst + 4) = hi;
    }
    __syncthreads();

    const int nkk = ntap * 4;
#pragma unroll 4
    for (int kk = 0; kk < nkk; ++kk) {
      const int kkg = kbase + kk;
      short8 A0 = *(const short8*)(aP0 + (size_t)kkg * 512);
      short8 A1 = *(const short8*)(aP1 + (size_t)kkg * 512);
      const short* b0 = Bs + col * BPITCH + kk * 16 + half * 8;
      const short* b1 = Bs + (32 + col) * BPITCH + kk * 16 + half * 8;
      short4a l0 = *(const short4a*)b0, h0 = *(const short4a*)(b0 + 4);
      short4a l1 = *(const short4a*)b1, h1 = *(const short4a*)(b1 + 4);
      short8 B0 = {l0[0], l0[1], l0[2], l0[3], h0[0], h0[1], h0[2], h0[3]};
      short8 B1 = {l1[0], l1[1], l1[2], l1[3], h1[0], h1[1], h1[2], h1[3]};
      acc00 = __builtin_amdgcn_mfma_f32_32x32x16_bf16(A0, B0, acc00, 0, 0, 0);
      acc01 = __builtin_amdgcn_mfma_f32_32x32x16_bf16(A0, B1, acc01, 0, 0, 0);
      acc10 = __builtin_amdgcn_mfma_f32_32x32x16_bf16(A1, B0, acc10, 0, 0, 0);
      acc11 = __builtin_amdgcn_mfma_f32_32x32x16_bf16(A1, B1, acc11, 0, 0, 0);
    }
  }

  const int pix0 = pixbase + col, pix1 = pixbase + 32 + col;
#pragma unroll
  for (int r = 0; r < 16; ++r) {
    const int rrow = (r & 3) + 8 * (r >> 2) + 4 * half;
    const int oc0 = w * 32 + rrow;
    const int oc1 = (w + 4) * 32 + rrow;
    const float bs0 = bias[oc0];
    out[((size_t)b * 216 + oc0) * HWP + pix0] = f2bf(acc00[r] + bs0);
    out[((size_t)b * 216 + oc0) * HWP + pix1] = f2bf(acc01[r] + bs0);
    if (oc1 < 216) {
      const float bs1 = bias[oc1];
      out[((size_t)b * 216 + oc1) * HWP + pix0] = f2bf(acc10[r] + bs1);
      out[((size_t)b * 216 + oc1) * HWP + pix1] = f2bf(acc11[r] + bs1);
    }
  }
}

// ---------------------------------------------------------------------------
// Fused DCN: phase 1 bilinear-sample into LDS (B-fragment order), phase 2
// K-split GEMM from LDS. Block (32,8)=4 waves, grid (288, BATCH).
// LDS: 36KB tile + 8.5KB reduction = 45.5KB -> 3 blocks/CU.
// ---------------------------------------------------------------------------
template <int D, bool LRELU, bool PMOUT>
__global__ __launch_bounds__(256) void dcn_fused(
    const short* __restrict__ xT,   // (b, hw, 64) bf16 pixel-major
    const short* __restrict__ om,   // (b, 216, hw) bf16
    const short* __restrict__ Wd,   // shuffled [tile(2)][kk(36)][lane][8]
    const float* __restrict__ bias, // (64)
    void* __restrict__ outv) {
  __shared__ short Ls[36 * 512];        // 36,864 B
  __shared__ float red[2][64][17];      // 8,704 B
  const int tx = threadIdx.x, ty = threadIdx.y;
  const int pb = blockIdx.x, b = blockIdx.y;

  // ---- phase 1: sample -> LDS ----
  {
    const int px = tx, dg = ty;
    const int pix = pb * 32 + px;
    const int yp = pix / WW, xp = pix % WW;
    const size_t bOM = (size_t)b * 216 * HWP;
    const short* xb = xT + (size_t)b * HWP * 64 + dg * 8;
    short* Sp = Ls + (size_t)((dg & 1) * 32 + px) * 8;

#pragma unroll
    for (int k = 0; k < 9; ++k) {
      float dy = bf2f(om[bOM + (size_t)(dg * 18 + 2 * k) * HWP + pix]);
      float dxv = bf2f(om[bOM + (size_t)(dg * 18 + 2 * k + 1) * HWP + pix]);
      float mr = bf2f(om[bOM + (size_t)(144 + dg * 9 + k) * HWP + pix]);
      float m = 1.f / (1.f + __expf(-mr));
      float py = (float)(yp + (k / 3 - 1) * D) + dy;
      float px_ = (float)(xp + (k % 3 - 1) * D) + dxv;
      float y0f = floorf(py), x0f = floorf(px_);
      float ly = py - y0f, lx = px_ - x0f;
      int y0 = (int)y0f, x0 = (int)x0f;
      int y1 = y0 + 1, x1 = x0 + 1;
      bool vy0 = (unsigned)y0 < (unsigned)HH, vy1 = (unsigned)y1 < (unsigned)HH;
      bool vx0 = (unsigned)x0 < (unsigned)WW, vx1 = (unsigned)x1 < (unsigned)WW;
      int cy0 = min(max(y0, 0), HH - 1), cy1 = min(max(y1, 0), HH - 1);
      int cx0 = min(max(x0, 0), WW - 1), cx1 = min(max(x1, 0), WW - 1);
      float w00 = (vy0 && vx0) ? (1.f - ly) * (1.f - lx) * m : 0.f;
      float w01 = (vy0 && vx1) ? (1.f - ly) * lx * m : 0.f;
      float w10 = (vy1 && vx0) ? ly * (1.f - lx) * m : 0.f;
      float w11 = (vy1 && vx1) ? ly * lx * m : 0.f;
      short8 s00 = *(const short8*)(xb + (size_t)(cy0 * WW + cx0) * 64);
      short8 s01 = *(const short8*)(xb + (size_t)(cy0 * WW + cx1) * 64);
      short8 s10 = *(const short8*)(xb + (size_t)(cy1 * WW + cx0) * 64);
      short8 s11 = *(const short8*)(xb + (size_t)(cy1 * WW + cx1) * 64);
      short8 pk;
#pragma unroll
      for (int cl = 0; cl < 8; ++cl) {
        float v = w00 * bf2f(s00[cl]) + w01 * bf2f(s01[cl]) +
                  w10 * bf2f(s10[cl]) + w11 * bf2f(s11[cl]);
        pk[cl] = f2bf(v);
      }
      const int kk = k * 4 + (dg >> 1);
      *(short8*)(Sp + (size_t)kk * 512) = pk;
    }
  }
  __syncthreads();

  // ---- phase 2: GEMM from LDS ----
  const int lid = ty * 32 + tx;
  const int lane = lid & 63, w = lid >> 6;
  const int col = lane & 31, half = lane >> 5;
  const int octile = w & 1, kh = w >> 1;
  const int pix = pb * 32 + col;

  const short* aP = Wd + ((size_t)(octile * 36) * 64 + lane) * 8;
  const short* bP = Ls + (size_t)lane * 8;

  f32x16 acc = {};
#pragma unroll 6
  for (int kk = 0; kk < 18; ++kk) {
    const int kkg = kh * 18 + kk;
    short8 A = *(const short8*)(aP + (size_t)kkg * 512);
    short8 B = *(const short8*)(bP + (size_t)kkg * 512);
    acc = __builtin_amdgcn_mfma_f32_32x32x16_bf16(A, B, acc, 0, 0, 0);
  }

  if (kh == 1) {
#pragma unroll
    for (int r = 0; r < 16; ++r) red[octile][lane][r] = acc[r];
  }
  __syncthreads();
  if (kh == 0) {
    if (PMOUT) {
      short* out = (short*)outv;
#pragma unroll
      for (int rg = 0; rg < 4; ++rg) {
        short4a pk;
#pragma unroll
        for (int i = 0; i < 4; ++i) {
          const int r = rg * 4 + i;
          const int oc = octile * 32 + i + 8 * rg + 4 * half;
          float v = acc[r] + red[octile][lane][r] + bias[oc];
          if (LRELU) v = (v >= 0.f) ? v : 0.1f * v;
          pk[i] = f2bf(v);
        }
        *(short4a*)(out + ((size_t)b * HWP + pix) * 64 + octile * 32 + 8 * rg + 4 * half) = pk;
      }
    } else {
      float* out = (float*)outv;
#pragma unroll
      for (int r = 0; r < 16; ++r) {
        const int oc = octile * 32 + (r & 3) + 8 * (r >> 2) + 4 * half;
        float v = acc[r] + red[octile][lane][r] + bias[oc];
        if (LRELU) v = (v >= 0.f) ? v : 0.1f * v;
        out[((size_t)b * NFEAT + oc) * HWP + pix] = v;
      }
    }
  }
}

// ---------------------------------------------------------------------------
extern "C" void kernel_launch(void* const* d_in, const int* in_sizes, int n_in,
                              void* d_out, int out_size, void* d_ws, size_t ws_size,
                              hipStream_t stream) {
  const float* nbr = (const float*)d_in[0];
  const float* ref = (const float*)d_in[1];
  auto f = [&](int i) { return (const float*)d_in[i]; };

  short* s0 = (short*)d_ws;
  const size_t PM = (size_t)BATCH * HWP * 64;   // 2,359,296 shorts
  short* omB = s0;                              // 7,962,624 shorts (bf16 now)
  short* refT = omB + 7962624;
  short* pmA = refT + PM;
  short* pmB = pmA + PM;
  short* pmC = pmB + PM;
  short* pmD = pmC + PM;
  short* pmE = pmD + PM;
  short* wbf = pmE + PM;                        // 589,824
  short* wdcn = wbf + 589824;                   // 147,456
  short* wgc = wdcn + 147456;                   // 188,416
  short* nbrT = (short*)d_out;                  // dead before final write

  // ---- weight prep ----
  prep_om<<<(4 * 147456 + 255) / 256, 256, 0, stream>>>(f(6), f(18), f(30), f(38), wbf);
  prep_dcnw<<<(4 * 36864 + 255) / 256, 256, 0, stream>>>(f(8), f(20), f(32), f(40), wdcn);

  static const int gSrc[12] = {2, 4, 10, 12, 14, 16, 22, 24, 26, 28, 34, 36};
  static const int gCat[12] = {1, 0, 1, 1, 0, 1, 1, 1, 0, 1, 1, 0};
  GwArgs ga;
  int gb = 0;
  const short* wg[12];
  for (int t = 0; t < 12; ++t) {
    ga.src[t] = f(gSrc[t]);
    ga.cat[t] = gCat[t];
    ga.base[t] = gb;
    wg[t] = wgc + gb;
    gb += gCat[t] ? 18432 : 10240;
  }
  ga.base[12] = gb;  // 188,416
  prep_gw<<<(gb + 255) / 256, 256, 0, stream>>>(ga, wgc);

  short* wbf_l3 = wbf;
  short* wbf_l2 = wbf + 147456;
  short* wbf_l1 = wbf + 2 * 147456;
  short* wbf_cas = wbf + 3 * 147456;
  short* wd_l3 = wdcn;
  short* wd_l2 = wdcn + 36864;
  short* wd_l1 = wdcn + 2 * 36864;
  short* wd_cas = wdcn + 3 * 36864;

  dim3 gcGrid(288, BATCH), gcBlk(64, 4);
  dim3 omGrid(144, BATCH), omBlk(64, 4);
  dim3 dfGrid(288, BATCH), dfBlk(32, 8);
  dim3 trGrid(HWP / 64, BATCH, 2), trBlk(64, 4);

  transpose_bf16<<<trGrid, trBlk, 0, stream>>>(nbr, nbrT, ref, refT);

  // ---- level 3 (dilation 5) ----
  gconv_mfma<true, true><<<gcGrid, gcBlk, 0, stream>>>(nbrT, refT, wg[0], f(3), pmA);
  gconv_mfma<false, true><<<gcGrid, gcBlk, 0, stream>>>(pmA, nullptr, wg[1], f(5), pmB);
  omconv_mfma<5><<<omGrid, omBlk, 0, stream>>>(pmB, wbf_l3, f(7), omB);
  dcn_fused<5, true, true><<<dfGrid, dfBlk, 0, stream>>>(nbrT, omB, wd_l3, f(9), pmC);
  // pmB = to_l3, pmC = tf_l3

  // ---- level 2 (dilation 3) ----
  gconv_mfma<true, true><<<gcGrid, gcBlk, 0, stream>>>(nbrT, refT, wg[2], f(11), pmA);
  gconv_mfma<true, true><<<gcGrid, gcBlk, 0, stream>>>(pmA, pmB, wg[3], f(13), pmD);
  gconv_mfma<false, true><<<gcGrid, gcBlk, 0, stream>>>(pmD, nullptr, wg[4], f(15), pmE);
  omconv_mfma<3><<<omGrid, omBlk, 0, stream>>>(pmE, wbf_l2, f(19), omB);
  dcn_fused<3, false, true><<<dfGrid, dfBlk, 0, stream>>>(nbrT, omB, wd_l2, f(21), pmD);
  gconv_mfma<true, true><<<gcGrid, gcBlk, 0, stream>>>(pmD, pmC, wg[5], f(17), pmA);
  // pmE = to_l2, pmA = tf_l2

  // ---- level 1 (dilation 1) ----
  gconv_mfma<true, true><<<gcGrid, gcBlk, 0, stream>>>(nbrT, refT, wg[6], f(23), pmC);
  gconv_mfma<true, true><<<gcGrid, gcBlk, 0, stream>>>(pmC, pmE, wg[7], f(25), pmD);
  gconv_mfma<false, true><<<gcGrid, gcBlk, 0, stream>>>(pmD, nullptr, wg[8], f(27), pmC);
  omconv_mfma<1><<<omGrid, omBlk, 0, stream>>>(pmC, wbf_l1, f(31), omB);
  dcn_fused<1, false, true><<<dfGrid, dfBlk, 0, stream>>>(nbrT, omB, wd_l1, f(33), pmD);
  gconv_mfma<true, false><<<gcGrid, gcBlk, 0, stream>>>(pmD, pmA, wg[9], f(29), pmB);
  // pmB = feat (no lrelu); nbrT (in d_out) now dead

  // ---- cascade (dilation 1) ----
  gconv_mfma<true, true><<<gcGrid, gcBlk, 0, stream>>>(pmB, refT, wg[10], f(35), pmC);
  gconv_mfma<false, true><<<gcGrid, gcBlk, 0, stream>>>(pmC, nullptr, wg[11], f(37), pmD);
  omconv_mfma<1><<<omGrid, omBlk, 0, stream>>>(pmD, wbf_cas, f(39), omB);
  dcn_fused<1, true, false><<<dfGrid, dfBlk, 0, stream>>>(pmB, omB, wd_cas, f(41), (float*)d_out);
}